// Round 13
// baseline (507.447 us; speedup 1.0000x reference)
//
#include <hip/hip_runtime.h>
#include <hip/hip_bf16.h>
#include <math.h>

// Problem constants
#define BATCH   2
#define NTOK    2048
#define DMODEL  1024
#define HEADS   16
#define DHEAD   64
#define KSEL    32
#define MROWS   (BATCH * NTOK)   // 4096
#define NBLK8   (NTOK / 8)       // 256 8-wide key blocks per row
#define TPW     2                // k-tiles per score workgroup (2: chunk0 gets 512 wg)

typedef short     bf16x8 __attribute__((ext_vector_type(8)));
typedef float     f32x4  __attribute__((ext_vector_type(4)));
typedef unsigned short ushort_t;
typedef unsigned long long u64;

#define GLOAD_LDS16(g, l) \
    __builtin_amdgcn_global_load_lds((const __attribute__((address_space(1))) void*)(g), \
                                     (__attribute__((address_space(3))) void*)(l), 16, 0, 0)

// ---------------------------------------------------------------------------
// bf16 helpers
// ---------------------------------------------------------------------------
__device__ __forceinline__ ushort_t f2bf(float f) {
    unsigned u = __float_as_uint(f);
    unsigned r = (u + 0x7FFFu + ((u >> 16) & 1u)) >> 16;
    return (ushort_t)r;
}
__device__ __forceinline__ float bf2f(ushort_t h) {
    return __uint_as_float(((unsigned)h) << 16);
}

__device__ __forceinline__ void conv_body(const float* __restrict__ in,
                                          ushort_t* __restrict__ hi,
                                          ushort_t* __restrict__ lo, int n, int i)
{
    if (i + 3 < n) {
        const float4 v = *(const float4*)(in + i);
        ushort4 ph, pl;
        ph.x = f2bf(v.x); pl.x = f2bf(v.x - bf2f(ph.x));
        ph.y = f2bf(v.y); pl.y = f2bf(v.y - bf2f(ph.y));
        ph.z = f2bf(v.z); pl.z = f2bf(v.z - bf2f(ph.z));
        ph.w = f2bf(v.w); pl.w = f2bf(v.w - bf2f(ph.w));
        *(ushort4*)(hi + i) = ph;
        *(ushort4*)(lo + i) = pl;
    }
}

__global__ __launch_bounds__(256) void conv_split(const float* __restrict__ in,
                                                  ushort_t* __restrict__ hi,
                                                  ushort_t* __restrict__ lo, int n)
{
    const int i = (blockIdx.x * 256 + threadIdx.x) * 4;
    conv_body(in, hi, lo, n, i);
}

// 5 arrays in ONE launch (grid.y picks slice; oversized slices exit on the
// bounds check). Slice 0 = x (n0 elems), slices 1..4 = weights (n1 elems).
__global__ __launch_bounds__(256) void conv_split5(const float* __restrict__ i0, ushort_t* __restrict__ h0, ushort_t* __restrict__ l0,
                                                   const float* __restrict__ i1, ushort_t* __restrict__ h1, ushort_t* __restrict__ l1,
                                                   const float* __restrict__ i2, ushort_t* __restrict__ h2, ushort_t* __restrict__ l2,
                                                   const float* __restrict__ i3, ushort_t* __restrict__ h3, ushort_t* __restrict__ l3,
                                                   const float* __restrict__ i4, ushort_t* __restrict__ h4, ushort_t* __restrict__ l4,
                                                   int n0, int n1)
{
    const int w = blockIdx.y;
    const float* in = (w == 0) ? i0 : (w == 1) ? i1 : (w == 2) ? i2 : (w == 3) ? i3 : i4;
    ushort_t* hi = (w == 0) ? h0 : (w == 1) ? h1 : (w == 2) ? h2 : (w == 3) ? h3 : h4;
    ushort_t* lo = (w == 0) ? l0 : (w == 1) ? l1 : (w == 2) ? l2 : (w == 3) ? l3 : l4;
    const int n = (w == 0) ? n0 : n1;
    const int i = (blockIdx.x * 256 + threadIdx.x) * 4;
    conv_body(in, hi, lo, n, i);
}

__global__ __launch_bounds__(256) void zero_fill(float* __restrict__ p, int n4)
{
    const int i = blockIdx.x * 256 + threadIdx.x;
    if (i < n4) ((float4*)p)[i] = (float4){0.f, 0.f, 0.f, 0.f};
}

// ---------------------------------------------------------------------------
// monotone key <-> float (bijective; order-preserving; 0 reserved for empty)
// ---------------------------------------------------------------------------
__device__ __forceinline__ unsigned mono_key(float f) {
    const unsigned u = __float_as_uint(f);
    return (u ^ (unsigned)(((int)u >> 31) | 0x80000000)) + 1u;
}
__device__ __forceinline__ float unmono(unsigned m) {
    const unsigned u = m - 1u;
    return __uint_as_float(u ^ (unsigned)(((int)(~u) >> 31) | 0x80000000));
}

// ---------------------------------------------------------------------------
// gemm_qkv_fused: Q/K/V projections in ONE kernel (shared A staging,
// 72 MFMAs per barrier). Natural blockIdx tile map. [best-measured form]
// ---------------------------------------------------------------------------
__global__ __launch_bounds__(256, 2) void gemm_qkv_fused(const ushort_t* __restrict__ xhi,
                                                         const ushort_t* __restrict__ xlo,
                                                         const ushort_t* __restrict__ wqh,
                                                         const ushort_t* __restrict__ wql,
                                                         const ushort_t* __restrict__ wkh,
                                                         const ushort_t* __restrict__ wkl,
                                                         const ushort_t* __restrict__ wvh,
                                                         const ushort_t* __restrict__ wvl,
                                                         const float* __restrict__ bq,
                                                         const float* __restrict__ bk,
                                                         const float* __restrict__ bv,
                                                         ushort_t* __restrict__ Qh,
                                                         ushort_t* __restrict__ Qm,
                                                         ushort_t* __restrict__ Ql,
                                                         ushort_t* __restrict__ Kh,
                                                         ushort_t* __restrict__ Km,
                                                         ushort_t* __restrict__ Kl,
                                                         float* __restrict__ Vws)
{
    __shared__ ushort_t smem[2 * 20480];   // 80 KB

    const int tid  = threadIdx.x;
    const int wave = tid >> 6;
    const int lane = tid & 63;
    const int fr   = lane & 15;
    const int k8   = lane >> 4;
    const int m0 = blockIdx.x * 128;
    const int n0 = blockIdx.y * 64;

    f32x4 acc[3][2][4];
#pragma unroll
    for (int w = 0; w < 3; ++w)
#pragma unroll
        for (int i = 0; i < 2; ++i)
#pragma unroll
            for (int j = 0; j < 4; ++j) acc[w][i][j] = (f32x4){0.f, 0.f, 0.f, 0.f};

#define STAGEF(bufsel, k0v) do {                                               \
        ushort_t* dst_ = smem + (size_t)(bufsel) * 20480;                      \
        _Pragma("unroll")                                                      \
        for (int i_ = 0; i_ < 2; ++i_) {                                       \
            const int c_ = i_ * 256 + tid;                                     \
            const int row_ = c_ >> 2;                                          \
            const int g_ = (c_ & 3) ^ ((row_ >> 1) & 3);                       \
            const size_t ga_ = (size_t)(m0 + row_) * DMODEL + (k0v) + g_ * 8;  \
            GLOAD_LDS16(xhi + ga_, dst_ + (size_t)c_ * 8);                     \
            GLOAD_LDS16(xlo + ga_, dst_ + 4096 + (size_t)c_ * 8);              \
        }                                                                      \
        {                                                                      \
            const int c_ = tid;                                                \
            const int row_ = c_ >> 2;                                          \
            const int g_ = (c_ & 3) ^ ((row_ >> 1) & 3);                       \
            const size_t gb_ = (size_t)(n0 + row_) * DMODEL + (k0v) + g_ * 8;  \
            GLOAD_LDS16(wqh + gb_, dst_ + 8192 + (size_t)c_ * 8);              \
            GLOAD_LDS16(wql + gb_, dst_ + 10240 + (size_t)c_ * 8);             \
            GLOAD_LDS16(wkh + gb_, dst_ + 12288 + (size_t)c_ * 8);             \
            GLOAD_LDS16(wkl + gb_, dst_ + 14336 + (size_t)c_ * 8);             \
            GLOAD_LDS16(wvh + gb_, dst_ + 16384 + (size_t)c_ * 8);             \
            GLOAD_LDS16(wvl + gb_, dst_ + 18432 + (size_t)c_ * 8);             \
        }                                                                      \
    } while (0)

    STAGEF(0, 0);
    int cur = 0;

    for (int k0 = 0; k0 < DMODEL; k0 += 32) {
        __syncthreads();                     // buf[cur] staged; prior reads done
        if (k0 + 32 < DMODEL) STAGEF(cur ^ 1, k0 + 32);

        const ushort_t* buf = smem + (size_t)cur * 20480;
        bf16x8 afh[2], afl[2];
#pragma unroll
        for (int mi = 0; mi < 2; ++mi) {
            const int r = wave * 32 + mi * 16 + fr;
            const int ro = r * 32 + (k8 ^ ((r >> 1) & 3)) * 8;
            afh[mi] = *(const bf16x8*)(buf + ro);
            afl[mi] = *(const bf16x8*)(buf + 4096 + ro);
        }

#pragma unroll
        for (int w = 0; w < 3; ++w) {
            const ushort_t* bb = buf + 8192 + w * 4096;
            bf16x8 bfh[4], bfl[4];
#pragma unroll
            for (int ni = 0; ni < 4; ++ni) {
                const int r = ni * 16 + fr;
                const int ro = r * 32 + (k8 ^ ((r >> 1) & 3)) * 8;
                bfh[ni] = *(const bf16x8*)(bb + ro);
                bfl[ni] = *(const bf16x8*)(bb + 2048 + ro);
            }
#pragma unroll
            for (int mi = 0; mi < 2; ++mi)
#pragma unroll
                for (int ni = 0; ni < 4; ++ni) {
                    acc[w][mi][ni] = __builtin_amdgcn_mfma_f32_16x16x32_bf16(afh[mi], bfl[ni], acc[w][mi][ni], 0, 0, 0);
                    acc[w][mi][ni] = __builtin_amdgcn_mfma_f32_16x16x32_bf16(afl[mi], bfh[ni], acc[w][mi][ni], 0, 0, 0);
                    acc[w][mi][ni] = __builtin_amdgcn_mfma_f32_16x16x32_bf16(afh[mi], bfh[ni], acc[w][mi][ni], 0, 0, 0);
                }
        }
        cur ^= 1;
    }
#undef STAGEF

    // ---- epilogue: Q (w=0) and K (w=1) -> 3-way split scatter; V (w=2) fp32
#pragma unroll
    for (int w = 0; w < 3; ++w) {
        const float* bias = (w == 0) ? bq : (w == 1) ? bk : bv;
        ushort_t* oh = (w == 0) ? Qh : Kh;
        ushort_t* om = (w == 0) ? Qm : Km;
        ushort_t* ol = (w == 0) ? Ql : Kl;
#pragma unroll
        for (int ni = 0; ni < 4; ++ni) {
            const int o = n0 + ni * 16 + (lane & 15);
            const float bvv = bias[o];
            const int hd = o >> 6;
            const int d  = o & 63;
#pragma unroll
            for (int mi = 0; mi < 2; ++mi) {
#pragma unroll
                for (int reg = 0; reg < 4; ++reg) {
                    const int m = m0 + wave * 32 + mi * 16 + ((lane >> 4) << 2) + reg;
                    const float v = acc[w][mi][ni][reg] + bvv;
                    const int bb = m >> 11;
                    const int n  = m & 2047;
                    const size_t off = (((size_t)(bb * HEADS + hd)) * NTOK + n) * DHEAD + d;
                    if (w == 2) {
                        Vws[off] = v;
                    } else {
                        const ushort_t h1 = f2bf(v);
                        const float r1 = v - bf2f(h1);
                        const ushort_t m1 = f2bf(r1);
                        const ushort_t l1 = f2bf(r1 - bf2f(m1));
                        oh[off] = h1; om[off] = m1; ol[off] = l1;
                    }
                }
            }
        }
    }
}

// ---------------------------------------------------------------------------
// Split-bf16 MFMA GEMM (2-buffer, Wo projection only). [best-measured form]
// ---------------------------------------------------------------------------
__global__ __launch_bounds__(256, 2) void gemm_split_mfma(const ushort_t* __restrict__ Ahi,
                                                          const ushort_t* __restrict__ Alo,
                                                          const ushort_t* __restrict__ Bhi,
                                                          const ushort_t* __restrict__ Blo,
                                                          const float* __restrict__ bias,
                                                          float* __restrict__ out)
{
    // per buffer: AH [0,4096) AL [4096,8192) BH [8192,10240) BL [10240,12288)
    __shared__ ushort_t smem[2 * 12288];   // 48 KB

    const int tid  = threadIdx.x;
    const int wave = tid >> 6;
    const int lane = tid & 63;
    const int fr   = lane & 15;
    const int k8   = lane >> 4;
    const int m0 = blockIdx.x * 128;
    const int n0 = blockIdx.y * 64;

    f32x4 acc[2][4];
#pragma unroll
    for (int i = 0; i < 2; ++i)
#pragma unroll
        for (int j = 0; j < 4; ++j) acc[i][j] = (f32x4){0.f, 0.f, 0.f, 0.f};

#define STAGE(bufsel, k0v) do {                                                \
        ushort_t* dst_ = smem + (size_t)(bufsel) * 12288;                      \
        _Pragma("unroll")                                                      \
        for (int i_ = 0; i_ < 2; ++i_) {                                       \
            const int c_ = i_ * 256 + tid;                                     \
            const int row_ = c_ >> 2;                                          \
            const int g_ = (c_ & 3) ^ ((row_ >> 1) & 3);                       \
            const size_t ga_ = (size_t)(m0 + row_) * DMODEL + (k0v) + g_ * 8;  \
            GLOAD_LDS16(Ahi + ga_, dst_ + (size_t)c_ * 8);                     \
            GLOAD_LDS16(Alo + ga_, dst_ + 4096 + (size_t)c_ * 8);              \
        }                                                                      \
        {                                                                      \
            const int c_ = tid;                                                \
            const int row_ = c_ >> 2;                                          \
            const int g_ = (c_ & 3) ^ ((row_ >> 1) & 3);                       \
            const size_t gb_ = (size_t)(n0 + row_) * DMODEL + (k0v) + g_ * 8;  \
            GLOAD_LDS16(Bhi + gb_, dst_ + 8192 + (size_t)c_ * 8);              \
            GLOAD_LDS16(Blo + gb_, dst_ + 10240 + (size_t)c_ * 8);             \
        }                                                                      \
    } while (0)

    STAGE(0, 0);
    int cur = 0;

    for (int k0 = 0; k0 < DMODEL; k0 += 32) {
        __syncthreads();                     // buf[cur] staged; prior reads done
        if (k0 + 32 < DMODEL) STAGE(cur ^ 1, k0 + 32);

        const ushort_t* buf = smem + (size_t)cur * 12288;
        bf16x8 afh[2], afl[2], bfh[4], bfl[4];
#pragma unroll
        for (int mi = 0; mi < 2; ++mi) {
            const int r = wave * 32 + mi * 16 + fr;
            const int ro = r * 32 + (k8 ^ ((r >> 1) & 3)) * 8;
            afh[mi] = *(const bf16x8*)(buf + ro);
            afl[mi] = *(const bf16x8*)(buf + 4096 + ro);
        }
#pragma unroll
        for (int ni = 0; ni < 4; ++ni) {
            const int r = ni * 16 + fr;
            const int ro = r * 32 + (k8 ^ ((r >> 1) & 3)) * 8;
            bfh[ni] = *(const bf16x8*)(buf + 8192 + ro);
            bfl[ni] = *(const bf16x8*)(buf + 10240 + ro);
        }

#pragma unroll
        for (int mi = 0; mi < 2; ++mi)
#pragma unroll
            for (int ni = 0; ni < 4; ++ni) {
                acc[mi][ni] = __builtin_amdgcn_mfma_f32_16x16x32_bf16(afh[mi], bfl[ni], acc[mi][ni], 0, 0, 0);
                acc[mi][ni] = __builtin_amdgcn_mfma_f32_16x16x32_bf16(afl[mi], bfh[ni], acc[mi][ni], 0, 0, 0);
                acc[mi][ni] = __builtin_amdgcn_mfma_f32_16x16x32_bf16(afh[mi], bfh[ni], acc[mi][ni], 0, 0, 0);
            }
        cur ^= 1;
    }
#undef STAGE

#pragma unroll
    for (int ni = 0; ni < 4; ++ni) {
        const int o = n0 + ni * 16 + (lane & 15);
        const float bv = bias[o];
#pragma unroll
        for (int mi = 0; mi < 2; ++mi) {
#pragma unroll
            for (int reg = 0; reg < 4; ++reg) {
                const int m = m0 + wave * 32 + mi * 16 + ((lane >> 4) << 2) + reg;
                out[(size_t)m * DMODEL + o] = acc[mi][ni][reg] + bv;
            }
        }
    }
}

// ---------------------------------------------------------------------------
// score_mfma v3: transposed MFMA (S^T tile = K·Q^T), fused kt loop.
// ---------------------------------------------------------------------------
__global__ __launch_bounds__(256, 3) void score_mfma(const ushort_t* __restrict__ Qh,
                                                     const ushort_t* __restrict__ Qm,
                                                     const ushort_t* __restrict__ Ql,
                                                     const ushort_t* __restrict__ Kh,
                                                     const ushort_t* __restrict__ Km,
                                                     const ushort_t* __restrict__ Kl,
                                                     unsigned* __restrict__ S,
                                                     unsigned* __restrict__ Smax,
                                                     int q0, int QC)
{
    const int ks = blockIdx.x;
    const int qt = blockIdx.y;
    const int bh = blockIdx.z;
    const int qbase = q0 + qt * 128;
    const int ktmax = ((qbase + 127) >> 6) + 1;   // tiles with any causal part
    const int kt0 = ks * TPW;
    if (kt0 >= ktmax) return;
    const int kt1 = (kt0 + TPW < ktmax) ? (kt0 + TPW) : ktmax;

    // 48 KB: 2 K buffers x 3 planes x 64 rows x 64 d
    __shared__ ushort_t smem[2 * 12288];

    const int tid  = threadIdx.x;
    const int wave = tid >> 6;
    const int lane = tid & 63;
    const int l15  = lane & 15;
    const int l4   = lane >> 4;

    const size_t qgbase = ((size_t)bh * NTOK + qbase) * DHEAD;

    // ---- Q fragments straight from global: qf[plane][j][h]
    bf16x8 qf[3][2][2];
#pragma unroll
    for (int p = 0; p < 3; ++p) {
        const ushort_t* Qp = (p == 0) ? Qh : (p == 1) ? Qm : Ql;
#pragma unroll
        for (int j = 0; j < 2; ++j) {
            const int r = wave * 32 + j * 16 + l15;
#pragma unroll
            for (int h = 0; h < 2; ++h)
                qf[p][j][h] = *(const bf16x8*)(Qp + qgbase + (size_t)r * DHEAD + (h * 4 + l4) * 8);
        }
    }

#define STAGE_K(bufsel, ktv) do {                                              \
        const size_t kg_ = ((size_t)bh * NTOK + (ktv) * 64) * DHEAD;           \
        _Pragma("unroll")                                                      \
        for (int i_ = 0; i_ < 2; ++i_) {                                       \
            const int c_ = i_ * 256 + tid;                                     \
            const int row_ = c_ >> 3;                                          \
            const int g_ = (c_ & 7) ^ (row_ & 7);                              \
            const size_t goff_ = kg_ + (size_t)row_ * DHEAD + g_ * 8;          \
            ushort_t* dst_ = smem + (bufsel) * 12288 + (size_t)c_ * 8;         \
            GLOAD_LDS16(Kh + goff_, dst_ + 0 * 4096);                          \
            GLOAD_LDS16(Km + goff_, dst_ + 1 * 4096);                          \
            GLOAD_LDS16(Kl + goff_, dst_ + 2 * 4096);                          \
        }                                                                      \
    } while (0)

    STAGE_K(0, kt0);
    __builtin_amdgcn_sched_barrier(0);
    asm volatile("s_waitcnt vmcnt(0)" ::: "memory");
    __builtin_amdgcn_s_barrier();
    __builtin_amdgcn_sched_barrier(0);

    int cur = 0;
    const size_t srowQ = (size_t)bh * QC;

    for (int kt = kt0; kt < kt1; ++kt) {
        const bool more = (kt + 1 < kt1);
        if (more) STAGE_K(cur ^ 1, kt + 1);
        __builtin_amdgcn_sched_barrier(0);   // pin staging loads before all else

        f32x4 acc[4][2];
#pragma unroll
        for (int m = 0; m < 4; ++m)
#pragma unroll
            for (int j = 0; j < 2; ++j) acc[m][j] = (f32x4){0.f, 0.f, 0.f, 0.f};

        const ushort_t* kb = smem + cur * 12288;
#pragma unroll
        for (int h = 0; h < 2; ++h) {
            bf16x8 kf[4];
            // ---- plane Kh: terms (kh,ql),(kh,qm),(kh,qh)
#pragma unroll
            for (int m = 0; m < 4; ++m) {
                const int r = m * 16 + l15;
                const int slot = (h * 4 + l4) ^ (r & 7);
                kf[m] = *(const bf16x8*)(kb + 0 * 4096 + (size_t)(r * 8 + slot) * 8);
            }
#pragma unroll
            for (int m = 0; m < 4; ++m)
#pragma unroll
                for (int j = 0; j < 2; ++j) {
                    acc[m][j] = __builtin_amdgcn_mfma_f32_16x16x32_bf16(kf[m], qf[2][j][h], acc[m][j], 0, 0, 0);
                    acc[m][j] = __builtin_amdgcn_mfma_f32_16x16x32_bf16(kf[m], qf[1][j][h], acc[m][j], 0, 0, 0);
                    acc[m][j] = __builtin_amdgcn_mfma_f32_16x16x32_bf16(kf[m], qf[0][j][h], acc[m][j], 0, 0, 0);
                }
            // ---- plane Km: terms (km,qm),(km,qh)
#pragma unroll
            for (int m = 0; m < 4; ++m) {
                const int r = m * 16 + l15;
                const int slot = (h * 4 + l4) ^ (r & 7);
                kf[m] = *(const bf16x8*)(kb + 1 * 4096 + (size_t)(r * 8 + slot) * 8);
            }
#pragma unroll
            for (int m = 0; m < 4; ++m)
#pragma unroll
                for (int j = 0; j < 2; ++j) {
                    acc[m][j] = __builtin_amdgcn_mfma_f32_16x16x32_bf16(kf[m], qf[1][j][h], acc[m][j], 0, 0, 0);
                    acc[m][j] = __builtin_amdgcn_mfma_f32_16x16x32_bf16(kf[m], qf[0][j][h], acc[m][j], 0, 0, 0);
                }
            // ---- plane Kl: term (kl,qh)
#pragma unroll
            for (int m = 0; m < 4; ++m) {
                const int r = m * 16 + l15;
                const int slot = (h * 4 + l4) ^ (r & 7);
                kf[m] = *(const bf16x8*)(kb + 2 * 4096 + (size_t)(r * 8 + slot) * 8);
            }
#pragma unroll
            for (int m = 0; m < 4; ++m)
#pragma unroll
                for (int j = 0; j < 2; ++j)
                    acc[m][j] = __builtin_amdgcn_mfma_f32_16x16x32_bf16(kf[m], qf[0][j][h], acc[m][j], 0, 0, 0);
        }

        // ---- epilogue: lane holds k = kt*64 + m*16 + l4*4 + reg, q = col
#pragma unroll
        for (int j = 0; j < 2; ++j) {
            const int qrow  = wave * 32 + j * 16 + l15;
            const int qlrow = qt * 128 + qrow;
            const int qglob = qbase + qrow;
            const size_t srow = (srowQ + qlrow) * NTOK;
            const size_t mrow = (srowQ + qlrow) * NBLK8;
#pragma unroll
            for (int m = 0; m < 4; ++m) {
                const int kcol0 = kt * 64 + m * 16 + (l4 << 2);
                uint4 kv;
                kv.x = mono_key(acc[m][j][0] * 0.125f);
                kv.y = mono_key(acc[m][j][1] * 0.125f);
                kv.z = mono_key(acc[m][j][2] * 0.125f);
                kv.w = mono_key(acc[m][j][3] * 0.125f);
                *(uint4*)(S + srow + kcol0) = kv;
                // causal-masked 8-wide block max: 3 in-reg max + 1 shfl
                unsigned cm = (kcol0     <= qglob) ? kv.x : 0u;
                unsigned t;
                t = (kcol0 + 1 <= qglob) ? kv.y : 0u; cm = (t > cm) ? t : cm;
                t = (kcol0 + 2 <= qglob) ? kv.z : 0u; cm = (t > cm) ? t : cm;
                t = (kcol0 + 3 <= qglob) ? kv.w : 0u; cm = (t > cm) ? t : cm;
                const unsigned o = __shfl_xor(cm, 16, 64);
                cm = (o > cm) ? o : cm;
                if ((lane & 16) == 0) {
                    const int gblk = kt * 8 + m * 2 + (lane >> 5);
                    Smax[mrow + gblk] = cm;
                }
            }
        }

        if (more) {
            asm volatile("s_waitcnt vmcnt(16)" ::: "memory");
            __builtin_amdgcn_s_barrier();
            __builtin_amdgcn_sched_barrier(0);
        }
        cur ^= 1;
    }
#undef STAGE_K
}

// ---------------------------------------------------------------------------
// select_v7: hierarchical exact top-KSEL; V-gather 4-wide ILP-unrolled.
// [best-measured form]
// ---------------------------------------------------------------------------
__global__ __launch_bounds__(256) void select_v7(const unsigned* __restrict__ S,
                                                 const unsigned* __restrict__ Smax,
                                                 const float* __restrict__ V,
                                                 float* __restrict__ ctx,
                                                 float* __restrict__ attn,
                                                 int q0, int QC)
{
    __shared__ int   sBlkAll[4][KSEL];
    __shared__ int   sIdxAll[4][KSEL];
    __shared__ float sEAll[4][KSEL];

    const int lane = threadIdx.x & 63;
    const int wave = threadIdx.x >> 6;
    const int ql = blockIdx.x;
    const int b  = blockIdx.y >> 2;
    const int hg = blockIdx.y & 3;
    const int h  = hg * 4 + wave;
    const int q  = q0 + ql;
    const int L  = q + 1;
    const int nsel = (L < KSEL) ? L : KSEL;
    const int nb = (L + 7) >> 3;           // real 8-blocks in this row

    const size_t bhx = (size_t)(b * HEADS + h);
    const unsigned* Srow = S + (bhx * QC + ql) * NTOK;
    const unsigned* Mrow = Smax + (bhx * QC + ql) * NBLK8;
    const float* Vb   = V + bhx * NTOK * DHEAD;
    float* ctxRow  = ctx + (((size_t)(b * NTOK + q)) * HEADS + h) * DHEAD;
    float* attnRow = attn + ((size_t)(b * NTOK + q)) * NTOK;
    int*   sBlk = sBlkAll[wave];
    int*   sIdx = sIdxAll[wave];
    float* sE   = sEAll[wave];

    // ---- stage 1: block maxima (4 per lane; beyond-nb slots are stale -> 0)
    const uint4 bm4 = *(const uint4*)(Mrow + lane * 4);
    unsigned bmax[4] = {bm4.x, bm4.y, bm4.z, bm4.w};
#pragma unroll
    for (int s = 0; s < 4; ++s)
        if (lane * 4 + s >= nb) bmax[s] = 0u;

    unsigned gmax = bmax[0];
    gmax = (bmax[1] > gmax) ? bmax[1] : gmax;
    gmax = (bmax[2] > gmax) ? bmax[2] : gmax;
    gmax = (bmax[3] > gmax) ? bmax[3] : gmax;
#pragma unroll
    for (int d = 1; d < 64; d <<= 1) {
        const unsigned o = __shfl_xor(gmax, d, 64);
        gmax = (o > gmax) ? o : gmax;
    }
    const float vmax = unmono(gmax);

    unsigned selb = 0u;
    unsigned blkLo = 1u;
    int nselb;
    if (nb <= KSEL) {
        nselb = nb;
#pragma unroll
        for (int s = 0; s < 4; ++s)
            if (lane * 4 + s < nb) selb |= 1u << s;
    } else {
        nselb = KSEL;
        unsigned lo = 1u, hi = gmax >> 16;
        while (lo < hi) {
            const unsigned mid = lo + ((hi - lo + 1u) >> 1);
            const unsigned midk = mid << 16;
            int cnt = 0;
#pragma unroll
            for (int s = 0; s < 4; ++s)
                cnt += __popcll(__ballot(bmax[s] >= midk));
            if (cnt >= KSEL) lo = mid; else hi = mid - 1u;
        }
        blkLo = lo;
        const unsigned Tkb = lo << 16;
        const unsigned Gkb = Tkb | 0xFFFFu;
        int cge = 0, cgt = 0;
#pragma unroll
        for (int s = 0; s < 4; ++s) {
            cge += __popcll(__ballot(bmax[s] >= Tkb));
            cgt += __popcll(__ballot(bmax[s] > Gkb));
        }
        if (cge == KSEL) {
#pragma unroll
            for (int s = 0; s < 4; ++s)
                selb |= (bmax[s] >= Tkb) ? (1u << s) : 0u;
        } else {
            unsigned bmb = 0u;
#pragma unroll
            for (int s = 0; s < 4; ++s) {
                selb |= (bmax[s] > Gkb) ? (1u << s) : 0u;
                bmb  |= (bmax[s] >= Tkb && bmax[s] <= Gkb) ? (1u << s) : 0u;
            }
            int k_tie = KSEL - cgt;
            while (k_tie > 0) {
                u64 best = 0;
                unsigned bmm = bmb;
                while (bmm) {
                    const int s = __builtin_ctz(bmm);
                    bmm &= bmm - 1u;
                    const unsigned gblk = (unsigned)(lane * 4 + s);
                    const u64 k = ((u64)bmax[s] << 32) | (unsigned)~gblk;
                    if (k > best) best = k;
                }
                u64 bb = best;
#pragma unroll
                for (int d = 1; d < 64; d <<= 1) {
                    const u64 o = __shfl_xor(bb, d, 64);
                    bb = (o > bb) ? o : bb;
                }
                const unsigned gblk = ~(unsigned)bb;
                if (lane == (int)(gblk >> 2)) {
                    const unsigned bit = 1u << (gblk & 3u);
                    selb |= bit;
                    bmb &= ~bit;
                }
                --k_tie;
            }
        }
    }

    // ---- compact selected block ids into LDS (ascending by block index)
    {
        const int cb = __popc(selb);
        int pfxb = cb;
#pragma unroll
        for (int d = 1; d < 64; d <<= 1) {
            const int t = __shfl_up(pfxb, d, 64);
            if (lane >= d) pfxb += t;
        }
        pfxb -= cb;
        unsigned mskb = selb;
        int posb = pfxb;
        while (mskb) {
            const int s = __builtin_ctz(mskb);
            mskb &= mskb - 1u;
            sBlk[posb++] = lane * 4 + s;
        }
    }
    __asm volatile("s_waitcnt lgkmcnt(0)" ::: "memory");

    // ---- stage 2: gather candidates (<=256, 4/lane)
    const int NC = nselb * 8;
    unsigned km[4];
    int idx[4];
#pragma unroll
    for (int c = 0; c < 4; ++c) {
        const int t = c * 64 + lane;
        unsigned m = 0u;
        int j = 0;
        if (t < NC) {
            const int blk = sBlk[t >> 3];
            j = blk * 8 + (t & 7);
            if (j < L) m = Srow[j];
        }
        km[c] = m;
        idx[c] = j;
    }

    // exact element threshold (seeded: T_elem >= 32nd block max)
    unsigned lo = blkLo, hi = gmax >> 16;
    while (lo < hi) {
        const unsigned mid = lo + ((hi - lo + 1u) >> 1);
        const unsigned midk = mid << 16;
        int cnt = 0;
#pragma unroll
        for (int c = 0; c < 4; ++c)
            cnt += __popcll(__ballot(km[c] >= midk));
        if (cnt >= nsel) lo = mid; else hi = mid - 1u;
    }
    const unsigned Tk = lo << 16;
    const unsigned Gk = Tk | 0xFFFFu;

    int cnt_ge = 0, cnt_gt = 0;
#pragma unroll
    for (int c = 0; c < 4; ++c) {
        cnt_ge += __popcll(__ballot(km[c] >= Tk));
        cnt_gt += __popcll(__ballot(km[c] > Gk));
    }

    unsigned selmask = 0u;
    if (cnt_ge == nsel) {
#pragma unroll
        for (int c = 0; c < 4; ++c)
            selmask |= (km[c] >= Tk) ? (1u << c) : 0u;
    } else {
        unsigned bmask = 0u;
#pragma unroll
        for (int c = 0; c < 4; ++c) {
            selmask |= (km[c] > Gk) ? (1u << c) : 0u;
            bmask   |= (km[c] >= Tk && km[c] <= Gk) ? (1u << c) : 0u;
        }
        int k_tie = nsel - cnt_gt;
        while (k_tie > 0) {
            u64 best = 0;
            unsigned bmm = bmask;
            while (bmm) {
                const int c = __builtin_ctz(bmm);
                bmm &= bmm - 1u;
                const int t = c * 64 + lane;
                const u64 k = ((u64)km[c] << 32) |
                              ((u64)(0xFFFFu ^ (unsigned)idx[c]) << 16) | (u64)t;
                if (k > best) best = k;
            }
            u64 bb = best;
#pragma unroll
            for (int d = 1; d < 64; d <<= 1) {
                const u64 o = __shfl_xor(bb, d, 64);
                bb = (o > bb) ? o : bb;
            }
            const unsigned tt = (unsigned)bb & 0xFFFFu;
            if (lane == (int)(tt & 63u)) {
                const unsigned bit = 1u << (tt >> 6);
                selmask |= bit;
                bmask &= ~bit;
            }
            --k_tie;
        }
    }

    // ---- softmax over selected, attn scatter, ctx gather
    const int csel = __popc(selmask);
    int pfx = csel;
#pragma unroll
    for (int d = 1; d < 64; d <<= 1) {
        const int t = __shfl_up(pfx, d, 64);
        if (lane >= d) pfx += t;
    }
    pfx -= csel;

    float esum = 0.f;
    unsigned msk = selmask;
    int pos = pfx;
    while (msk) {
        const int c = __builtin_ctz(msk);
        msk &= msk - 1u;
        const float e = __expf(unmono(km[c]) - vmax);
        esum += e;
        sIdx[pos] = idx[c];
        sE[pos] = e;
        ++pos;
    }

    float Z = esum;
#pragma unroll
    for (int d = 1; d < 64; d <<= 1) Z += __shfl_xor(Z, d, 64);
    const float rcpZ = 1.0f / Z;

    msk = selmask;
    pos = pfx;
    while (msk) {
        const int c = __builtin_ctz(msk);
        msk &= msk - 1u;
        const float w = sE[pos] * rcpZ;
        ++pos;
        atomicAdd(&attnRow[idx[c]], w * (1.0f / (float)HEADS));
    }

    // ---- ctx gather: 4-wide unroll, 4 independent partial sums (ILP)
    {
        float a0 = 0.f, a1 = 0.f, a2 = 0.f, a3 = 0.f;
        int i = 0;
#pragma unroll 2
        for (; i + 4 <= nsel; i += 4) {
            const int i0 = sIdx[i],     i1 = sIdx[i + 1];
            const int i2 = sIdx[i + 2], i3 = sIdx[i + 3];
            const float w0 = sE[i]     * rcpZ, w1 = sE[i + 1] * rcpZ;
            const float w2 = sE[i + 2] * rcpZ, w3 = sE[i + 3] * rcpZ;
            a0 += w0 * Vb[(size_t)i0 * DHEAD + lane];
            a1 += w1 * Vb[(size_t)i1 * DHEAD + lane];
            a2 += w2 * Vb[(size_t)i2 * DHEAD + lane];
            a3 += w3 * Vb[(size_t)i3 * DHEAD + lane];
        }
        for (; i < nsel; ++i)
            a0 += sE[i] * rcpZ * Vb[(size_t)sIdx[i] * DHEAD + lane];
        ctxRow[lane] = (a0 + a1) + (a2 + a3);
    }
}

// ---------------------------------------------------------------------------
extern "C" void kernel_launch(void* const* d_in, const int* in_sizes, int n_in,
                              void* d_out, int out_size, void* d_ws, size_t ws_size,
                              hipStream_t stream) {
    const float* x  = (const float*)d_in[0];
    const float* Wq = (const float*)d_in[1];
    const float* bq = (const float*)d_in[2];
    const float* Wk = (const float*)d_in[3];
    const float* bk = (const float*)d_in[4];
    const float* Wv = (const float*)d_in[5];
    const float* bv = (const float*)d_in[6];
    const float* Wo = (const float*)d_in[7];
    const float* bo = (const float*)d_in[8];

    const size_t MB = 1ull << 20;
    char* wsb = (char*)d_ws;
    float*    Vws = (float*)(wsb + 0 * MB);     // 16 MB fp32 [b,h,n,d]
    float*    ctx = (float*)(wsb + 16 * MB);    // 16 MB fp32
    ushort_t* xhi = (ushort_t*)(wsb + 32 * MB); // 8 MB
    ushort_t* xlo = (ushort_t*)(wsb + 40 * MB); // 8 MB
    ushort_t* wqh = (ushort_t*)(wsb + 48 * MB); // 2 MB each
    ushort_t* wql = (ushort_t*)(wsb + 50 * MB);
    ushort_t* wkh = (ushort_t*)(wsb + 52 * MB);
    ushort_t* wkl = (ushort_t*)(wsb + 54 * MB);
    ushort_t* wvh = (ushort_t*)(wsb + 56 * MB);
    ushort_t* wvl = (ushort_t*)(wsb + 58 * MB);
    ushort_t* woh = (ushort_t*)(wsb + 60 * MB);
    ushort_t* wol = (ushort_t*)(wsb + 62 * MB);
    ushort_t* Qh  = (ushort_t*)(wsb + 64 * MB); // 8 MB each, [b,h,n,d]
    ushort_t* Qm  = (ushort_t*)(wsb + 72 * MB);
    ushort_t* Ql  = (ushort_t*)(wsb + 80 * MB);
    ushort_t* Kh  = (ushort_t*)(wsb + 88 * MB);
    ushort_t* Km  = (ushort_t*)(wsb + 96 * MB);
    ushort_t* Kl  = (ushort_t*)(wsb + 104 * MB);
    ushort_t* cxh = xhi;   // reuse (x splits dead after QKV projections)
    ushort_t* cxl = xlo;

    float* y    = (float*)d_out;
    float* attn = y + (size_t)BATCH * NTOK * DMODEL;

    const int NX = MROWS * DMODEL;
    const int NW = DMODEL * DMODEL;

    // ---- bf16 split conversions: x + 4 weights in ONE launch
    {
        dim3 cgrid(NX / (256 * 4), 5);
        conv_split5<<<cgrid, 256, 0, stream>>>(x, xhi, xlo,
                                               Wq, wqh, wql,
                                               Wk, wkh, wkl,
                                               Wv, wvh, wvl,
                                               Wo, woh, wol, NX, NW);
    }

    // ---- fused Q/K/V projection (single kernel, shared A staging)
    dim3 ggrid(MROWS / 128, DMODEL / 64);
    gemm_qkv_fused<<<ggrid, 256, 0, stream>>>(xhi, xlo,
                                              wqh, wql, wkh, wkl, wvh, wvl,
                                              bq, bk, bv,
                                              Qh, Qm, Ql, Kh, Km, Kl, Vws);

    // ---- attention: q-chunk capped at 512 (S chunk 151 MB = LLC-resident)
    const size_t base_bytes = 112 * MB;
    const size_t avail = (ws_size > base_bytes) ? ws_size - base_bytes : 0;
    int QC = 128;
    for (int cand = 512; cand >= 128; cand >>= 1) {
        const size_t need = (size_t)BATCH * HEADS * cand * (size_t)(NTOK + NBLK8) * sizeof(unsigned);
        if (need <= avail) { QC = cand; break; }
    }
    unsigned* Smax = (unsigned*)(wsb + base_bytes);
    unsigned* Sws  = (unsigned*)(wsb + base_bytes +
                                 (size_t)BATCH * HEADS * QC * NBLK8 * sizeof(unsigned));

    const int nattn4 = BATCH * NTOK * NTOK / 4;
    zero_fill<<<(nattn4 + 255) / 256, 256, 0, stream>>>(attn, nattn4);
    for (int q0 = 0; q0 < NTOK; q0 += QC) {
        const int ktm = (q0 + QC) >> 6;
        dim3 sgrid((ktm + TPW - 1) / TPW, QC / 128, BATCH * HEADS);
        score_mfma<<<sgrid, 256, 0, stream>>>(Qh, Qm, Ql, Kh, Km, Kl, Sws, Smax, q0, QC);
        dim3 selgrid(QC, BATCH * 4);
        select_v7<<<selgrid, 256, 0, stream>>>(Sws, Smax, Vws, ctx, attn, q0, QC);
    }

    // ---- output projection
    conv_split<<<NX / (256 * 4), 256, 0, stream>>>(ctx, cxh, cxl, NX);
    gemm_split_mfma<<<ggrid, 256, 0, stream>>>(cxh, cxl, woh, wol, bo, y);
}

// Round 14
// 498.930 us; speedup vs baseline: 1.0171x; 1.0171x over previous
//
#include <hip/hip_runtime.h>
#include <hip/hip_bf16.h>
#include <math.h>

// Problem constants
#define BATCH   2
#define NTOK    2048
#define DMODEL  1024
#define HEADS   16
#define DHEAD   64
#define KSEL    32
#define MROWS   (BATCH * NTOK)   // 4096
#define NBLK8   (NTOK / 8)       // 256 8-wide key blocks per row
#define TPW     4                // k-tiles per score workgroup (best-measured)

typedef short     bf16x8 __attribute__((ext_vector_type(8)));
typedef float     f32x4  __attribute__((ext_vector_type(4)));
typedef unsigned short ushort_t;
typedef unsigned long long u64;

#define GLOAD_LDS16(g, l) \
    __builtin_amdgcn_global_load_lds((const __attribute__((address_space(1))) void*)(g), \
                                     (__attribute__((address_space(3))) void*)(l), 16, 0, 0)

// ---------------------------------------------------------------------------
// bf16 helpers
// ---------------------------------------------------------------------------
__device__ __forceinline__ ushort_t f2bf(float f) {
    unsigned u = __float_as_uint(f);
    unsigned r = (u + 0x7FFFu + ((u >> 16) & 1u)) >> 16;
    return (ushort_t)r;
}
__device__ __forceinline__ float bf2f(ushort_t h) {
    return __uint_as_float(((unsigned)h) << 16);
}

__device__ __forceinline__ void conv_body(const float* __restrict__ in,
                                          ushort_t* __restrict__ hi,
                                          ushort_t* __restrict__ lo, int n, int i)
{
    if (i + 3 < n) {
        const float4 v = *(const float4*)(in + i);
        ushort4 ph, pl;
        ph.x = f2bf(v.x); pl.x = f2bf(v.x - bf2f(ph.x));
        ph.y = f2bf(v.y); pl.y = f2bf(v.y - bf2f(ph.y));
        ph.z = f2bf(v.z); pl.z = f2bf(v.z - bf2f(ph.z));
        ph.w = f2bf(v.w); pl.w = f2bf(v.w - bf2f(ph.w));
        *(ushort4*)(hi + i) = ph;
        *(ushort4*)(lo + i) = pl;
    }
}

__global__ __launch_bounds__(256) void conv_split(const float* __restrict__ in,
                                                  ushort_t* __restrict__ hi,
                                                  ushort_t* __restrict__ lo, int n)
{
    const int i = (blockIdx.x * 256 + threadIdx.x) * 4;
    conv_body(in, hi, lo, n, i);
}

// 4 equal-size arrays in one launch (grid.y = which)
__global__ __launch_bounds__(256) void conv_split4(const float* __restrict__ i0, ushort_t* __restrict__ h0, ushort_t* __restrict__ l0,
                                                   const float* __restrict__ i1, ushort_t* __restrict__ h1, ushort_t* __restrict__ l1,
                                                   const float* __restrict__ i2, ushort_t* __restrict__ h2, ushort_t* __restrict__ l2,
                                                   const float* __restrict__ i3, ushort_t* __restrict__ h3, ushort_t* __restrict__ l3,
                                                   int n)
{
    const int w = blockIdx.y;
    const float* in = (w == 0) ? i0 : (w == 1) ? i1 : (w == 2) ? i2 : i3;
    ushort_t* hi = (w == 0) ? h0 : (w == 1) ? h1 : (w == 2) ? h2 : h3;
    ushort_t* lo = (w == 0) ? l0 : (w == 1) ? l1 : (w == 2) ? l2 : l3;
    const int i = (blockIdx.x * 256 + threadIdx.x) * 4;
    conv_body(in, hi, lo, n, i);
}

__global__ __launch_bounds__(256) void zero_fill(float* __restrict__ p, int n4)
{
    const int i = blockIdx.x * 256 + threadIdx.x;
    if (i < n4) ((float4*)p)[i] = (float4){0.f, 0.f, 0.f, 0.f};
}

// ---------------------------------------------------------------------------
// monotone key <-> float (bijective; order-preserving; 0 reserved for empty)
// ---------------------------------------------------------------------------
__device__ __forceinline__ unsigned mono_key(float f) {
    const unsigned u = __float_as_uint(f);
    return (u ^ (unsigned)(((int)u >> 31) | 0x80000000)) + 1u;
}
__device__ __forceinline__ float unmono(unsigned m) {
    const unsigned u = m - 1u;
    return __uint_as_float(u ^ (unsigned)(((int)(~u) >> 31) | 0x80000000));
}

// ---------------------------------------------------------------------------
// gemm_qkv_fused: Q/K/V projections in ONE kernel (shared A staging,
// 72 MFMAs per barrier). Natural blockIdx tile map. [best-measured form]
// ---------------------------------------------------------------------------
__global__ __launch_bounds__(256, 2) void gemm_qkv_fused(const ushort_t* __restrict__ xhi,
                                                         const ushort_t* __restrict__ xlo,
                                                         const ushort_t* __restrict__ wqh,
                                                         const ushort_t* __restrict__ wql,
                                                         const ushort_t* __restrict__ wkh,
                                                         const ushort_t* __restrict__ wkl,
                                                         const ushort_t* __restrict__ wvh,
                                                         const ushort_t* __restrict__ wvl,
                                                         const float* __restrict__ bq,
                                                         const float* __restrict__ bk,
                                                         const float* __restrict__ bv,
                                                         ushort_t* __restrict__ Qh,
                                                         ushort_t* __restrict__ Qm,
                                                         ushort_t* __restrict__ Ql,
                                                         ushort_t* __restrict__ Kh,
                                                         ushort_t* __restrict__ Km,
                                                         ushort_t* __restrict__ Kl,
                                                         float* __restrict__ Vws)
{
    __shared__ ushort_t smem[2 * 20480];   // 80 KB

    const int tid  = threadIdx.x;
    const int wave = tid >> 6;
    const int lane = tid & 63;
    const int fr   = lane & 15;
    const int k8   = lane >> 4;
    const int m0 = blockIdx.x * 128;
    const int n0 = blockIdx.y * 64;

    f32x4 acc[3][2][4];
#pragma unroll
    for (int w = 0; w < 3; ++w)
#pragma unroll
        for (int i = 0; i < 2; ++i)
#pragma unroll
            for (int j = 0; j < 4; ++j) acc[w][i][j] = (f32x4){0.f, 0.f, 0.f, 0.f};

#define STAGEF(bufsel, k0v) do {                                               \
        ushort_t* dst_ = smem + (size_t)(bufsel) * 20480;                      \
        _Pragma("unroll")                                                      \
        for (int i_ = 0; i_ < 2; ++i_) {                                       \
            const int c_ = i_ * 256 + tid;                                     \
            const int row_ = c_ >> 2;                                          \
            const int g_ = (c_ & 3) ^ ((row_ >> 1) & 3);                       \
            const size_t ga_ = (size_t)(m0 + row_) * DMODEL + (k0v) + g_ * 8;  \
            GLOAD_LDS16(xhi + ga_, dst_ + (size_t)c_ * 8);                     \
            GLOAD_LDS16(xlo + ga_, dst_ + 4096 + (size_t)c_ * 8);              \
        }                                                                      \
        {                                                                      \
            const int c_ = tid;                                                \
            const int row_ = c_ >> 2;                                          \
            const int g_ = (c_ & 3) ^ ((row_ >> 1) & 3);                       \
            const size_t gb_ = (size_t)(n0 + row_) * DMODEL + (k0v) + g_ * 8;  \
            GLOAD_LDS16(wqh + gb_, dst_ + 8192 + (size_t)c_ * 8);              \
            GLOAD_LDS16(wql + gb_, dst_ + 10240 + (size_t)c_ * 8);             \
            GLOAD_LDS16(wkh + gb_, dst_ + 12288 + (size_t)c_ * 8);             \
            GLOAD_LDS16(wkl + gb_, dst_ + 14336 + (size_t)c_ * 8);             \
            GLOAD_LDS16(wvh + gb_, dst_ + 16384 + (size_t)c_ * 8);             \
            GLOAD_LDS16(wvl + gb_, dst_ + 18432 + (size_t)c_ * 8);             \
        }                                                                      \
    } while (0)

    STAGEF(0, 0);
    int cur = 0;

    for (int k0 = 0; k0 < DMODEL; k0 += 32) {
        __syncthreads();                     // buf[cur] staged; prior reads done
        if (k0 + 32 < DMODEL) STAGEF(cur ^ 1, k0 + 32);

        const ushort_t* buf = smem + (size_t)cur * 20480;
        bf16x8 afh[2], afl[2];
#pragma unroll
        for (int mi = 0; mi < 2; ++mi) {
            const int r = wave * 32 + mi * 16 + fr;
            const int ro = r * 32 + (k8 ^ ((r >> 1) & 3)) * 8;
            afh[mi] = *(const bf16x8*)(buf + ro);
            afl[mi] = *(const bf16x8*)(buf + 4096 + ro);
        }

#pragma unroll
        for (int w = 0; w < 3; ++w) {
            const ushort_t* bb = buf + 8192 + w * 4096;
            bf16x8 bfh[4], bfl[4];
#pragma unroll
            for (int ni = 0; ni < 4; ++ni) {
                const int r = ni * 16 + fr;
                const int ro = r * 32 + (k8 ^ ((r >> 1) & 3)) * 8;
                bfh[ni] = *(const bf16x8*)(bb + ro);
                bfl[ni] = *(const bf16x8*)(bb + 2048 + ro);
            }
#pragma unroll
            for (int mi = 0; mi < 2; ++mi)
#pragma unroll
                for (int ni = 0; ni < 4; ++ni) {
                    acc[w][mi][ni] = __builtin_amdgcn_mfma_f32_16x16x32_bf16(afh[mi], bfl[ni], acc[w][mi][ni], 0, 0, 0);
                    acc[w][mi][ni] = __builtin_amdgcn_mfma_f32_16x16x32_bf16(afl[mi], bfh[ni], acc[w][mi][ni], 0, 0, 0);
                    acc[w][mi][ni] = __builtin_amdgcn_mfma_f32_16x16x32_bf16(afh[mi], bfh[ni], acc[w][mi][ni], 0, 0, 0);
                }
        }
        cur ^= 1;
    }
#undef STAGEF

    // ---- epilogue: Q (w=0) and K (w=1) -> 3-way split scatter; V (w=2) fp32
#pragma unroll
    for (int w = 0; w < 3; ++w) {
        const float* bias = (w == 0) ? bq : (w == 1) ? bk : bv;
        ushort_t* oh = (w == 0) ? Qh : Kh;
        ushort_t* om = (w == 0) ? Qm : Km;
        ushort_t* ol = (w == 0) ? Ql : Kl;
#pragma unroll
        for (int ni = 0; ni < 4; ++ni) {
            const int o = n0 + ni * 16 + (lane & 15);
            const float bvv = bias[o];
            const int hd = o >> 6;
            const int d  = o & 63;
#pragma unroll
            for (int mi = 0; mi < 2; ++mi) {
#pragma unroll
                for (int reg = 0; reg < 4; ++reg) {
                    const int m = m0 + wave * 32 + mi * 16 + ((lane >> 4) << 2) + reg;
                    const float v = acc[w][mi][ni][reg] + bvv;
                    const int bb = m >> 11;
                    const int n  = m & 2047;
                    const size_t off = (((size_t)(bb * HEADS + hd)) * NTOK + n) * DHEAD + d;
                    if (w == 2) {
                        Vws[off] = v;
                    } else {
                        const ushort_t h1 = f2bf(v);
                        const float r1 = v - bf2f(h1);
                        const ushort_t m1 = f2bf(r1);
                        const ushort_t l1 = f2bf(r1 - bf2f(m1));
                        oh[off] = h1; om[off] = m1; ol[off] = l1;
                    }
                }
            }
        }
    }
}

// ---------------------------------------------------------------------------
// Split-bf16 MFMA GEMM (2-buffer, Wo projection only). [best-measured form]
// ---------------------------------------------------------------------------
__global__ __launch_bounds__(256, 2) void gemm_split_mfma(const ushort_t* __restrict__ Ahi,
                                                          const ushort_t* __restrict__ Alo,
                                                          const ushort_t* __restrict__ Bhi,
                                                          const ushort_t* __restrict__ Blo,
                                                          const float* __restrict__ bias,
                                                          float* __restrict__ out)
{
    // per buffer: AH [0,4096) AL [4096,8192) BH [8192,10240) BL [10240,12288)
    __shared__ ushort_t smem[2 * 12288];   // 48 KB

    const int tid  = threadIdx.x;
    const int wave = tid >> 6;
    const int lane = tid & 63;
    const int fr   = lane & 15;
    const int k8   = lane >> 4;
    const int m0 = blockIdx.x * 128;
    const int n0 = blockIdx.y * 64;

    f32x4 acc[2][4];
#pragma unroll
    for (int i = 0; i < 2; ++i)
#pragma unroll
        for (int j = 0; j < 4; ++j) acc[i][j] = (f32x4){0.f, 0.f, 0.f, 0.f};

#define STAGE(bufsel, k0v) do {                                                \
        ushort_t* dst_ = smem + (size_t)(bufsel) * 12288;                      \
        _Pragma("unroll")                                                      \
        for (int i_ = 0; i_ < 2; ++i_) {                                       \
            const int c_ = i_ * 256 + tid;                                     \
            const int row_ = c_ >> 2;                                          \
            const int g_ = (c_ & 3) ^ ((row_ >> 1) & 3);                       \
            const size_t ga_ = (size_t)(m0 + row_) * DMODEL + (k0v) + g_ * 8;  \
            GLOAD_LDS16(Ahi + ga_, dst_ + (size_t)c_ * 8);                     \
            GLOAD_LDS16(Alo + ga_, dst_ + 4096 + (size_t)c_ * 8);              \
        }                                                                      \
        {                                                                      \
            const int c_ = tid;                                                \
            const int row_ = c_ >> 2;                                          \
            const int g_ = (c_ & 3) ^ ((row_ >> 1) & 3);                       \
            const size_t gb_ = (size_t)(n0 + row_) * DMODEL + (k0v) + g_ * 8;  \
            GLOAD_LDS16(Bhi + gb_, dst_ + 8192 + (size_t)c_ * 8);              \
            GLOAD_LDS16(Blo + gb_, dst_ + 10240 + (size_t)c_ * 8);             \
        }                                                                      \
    } while (0)

    STAGE(0, 0);
    int cur = 0;

    for (int k0 = 0; k0 < DMODEL; k0 += 32) {
        __syncthreads();                     // buf[cur] staged; prior reads done
        if (k0 + 32 < DMODEL) STAGE(cur ^ 1, k0 + 32);

        const ushort_t* buf = smem + (size_t)cur * 12288;
        bf16x8 afh[2], afl[2], bfh[4], bfl[4];
#pragma unroll
        for (int mi = 0; mi < 2; ++mi) {
            const int r = wave * 32 + mi * 16 + fr;
            const int ro = r * 32 + (k8 ^ ((r >> 1) & 3)) * 8;
            afh[mi] = *(const bf16x8*)(buf + ro);
            afl[mi] = *(const bf16x8*)(buf + 4096 + ro);
        }
#pragma unroll
        for (int ni = 0; ni < 4; ++ni) {
            const int r = ni * 16 + fr;
            const int ro = r * 32 + (k8 ^ ((r >> 1) & 3)) * 8;
            bfh[ni] = *(const bf16x8*)(buf + 8192 + ro);
            bfl[ni] = *(const bf16x8*)(buf + 10240 + ro);
        }

#pragma unroll
        for (int mi = 0; mi < 2; ++mi)
#pragma unroll
            for (int ni = 0; ni < 4; ++ni) {
                acc[mi][ni] = __builtin_amdgcn_mfma_f32_16x16x32_bf16(afh[mi], bfl[ni], acc[mi][ni], 0, 0, 0);
                acc[mi][ni] = __builtin_amdgcn_mfma_f32_16x16x32_bf16(afl[mi], bfh[ni], acc[mi][ni], 0, 0, 0);
                acc[mi][ni] = __builtin_amdgcn_mfma_f32_16x16x32_bf16(afh[mi], bfh[ni], acc[mi][ni], 0, 0, 0);
            }
        cur ^= 1;
    }
#undef STAGE

#pragma unroll
    for (int ni = 0; ni < 4; ++ni) {
        const int o = n0 + ni * 16 + (lane & 15);
        const float bv = bias[o];
#pragma unroll
        for (int mi = 0; mi < 2; ++mi) {
#pragma unroll
            for (int reg = 0; reg < 4; ++reg) {
                const int m = m0 + wave * 32 + mi * 16 + ((lane >> 4) << 2) + reg;
                out[(size_t)m * DMODEL + o] = acc[mi][ni][reg] + bv;
            }
        }
    }
}

// ---------------------------------------------------------------------------
// score_mfma v3: transposed MFMA (S^T tile = K·Q^T), fused kt loop.
// ---------------------------------------------------------------------------
__global__ __launch_bounds__(256, 3) void score_mfma(const ushort_t* __restrict__ Qh,
                                                     const ushort_t* __restrict__ Qm,
                                                     const ushort_t* __restrict__ Ql,
                                                     const ushort_t* __restrict__ Kh,
                                                     const ushort_t* __restrict__ Km,
                                                     const ushort_t* __restrict__ Kl,
                                                     unsigned* __restrict__ S,
                                                     unsigned* __restrict__ Smax,
                                                     int q0, int QC)
{
    const int ks = blockIdx.x;
    const int qt = blockIdx.y;
    const int bh = blockIdx.z;
    const int qbase = q0 + qt * 128;
    const int ktmax = ((qbase + 127) >> 6) + 1;   // tiles with any causal part
    const int kt0 = ks * TPW;
    if (kt0 >= ktmax) return;
    const int kt1 = (kt0 + TPW < ktmax) ? (kt0 + TPW) : ktmax;

    // 48 KB: 2 K buffers x 3 planes x 64 rows x 64 d
    __shared__ ushort_t smem[2 * 12288];

    const int tid  = threadIdx.x;
    const int wave = tid >> 6;
    const int lane = tid & 63;
    const int l15  = lane & 15;
    const int l4   = lane >> 4;

    const size_t qgbase = ((size_t)bh * NTOK + qbase) * DHEAD;

    // ---- Q fragments straight from global: qf[plane][j][h]
    bf16x8 qf[3][2][2];
#pragma unroll
    for (int p = 0; p < 3; ++p) {
        const ushort_t* Qp = (p == 0) ? Qh : (p == 1) ? Qm : Ql;
#pragma unroll
        for (int j = 0; j < 2; ++j) {
            const int r = wave * 32 + j * 16 + l15;
#pragma unroll
            for (int h = 0; h < 2; ++h)
                qf[p][j][h] = *(const bf16x8*)(Qp + qgbase + (size_t)r * DHEAD + (h * 4 + l4) * 8);
        }
    }

#define STAGE_K(bufsel, ktv) do {                                              \
        const size_t kg_ = ((size_t)bh * NTOK + (ktv) * 64) * DHEAD;           \
        _Pragma("unroll")                                                      \
        for (int i_ = 0; i_ < 2; ++i_) {                                       \
            const int c_ = i_ * 256 + tid;                                     \
            const int row_ = c_ >> 3;                                          \
            const int g_ = (c_ & 7) ^ (row_ & 7);                              \
            const size_t goff_ = kg_ + (size_t)row_ * DHEAD + g_ * 8;          \
            ushort_t* dst_ = smem + (bufsel) * 12288 + (size_t)c_ * 8;         \
            GLOAD_LDS16(Kh + goff_, dst_ + 0 * 4096);                          \
            GLOAD_LDS16(Km + goff_, dst_ + 1 * 4096);                          \
            GLOAD_LDS16(Kl + goff_, dst_ + 2 * 4096);                          \
        }                                                                      \
    } while (0)

    STAGE_K(0, kt0);
    __builtin_amdgcn_sched_barrier(0);
    asm volatile("s_waitcnt vmcnt(0)" ::: "memory");
    __builtin_amdgcn_s_barrier();
    __builtin_amdgcn_sched_barrier(0);

    int cur = 0;
    const size_t srowQ = (size_t)bh * QC;

    for (int kt = kt0; kt < kt1; ++kt) {
        const bool more = (kt + 1 < kt1);
        if (more) STAGE_K(cur ^ 1, kt + 1);
        __builtin_amdgcn_sched_barrier(0);   // pin staging loads before all else

        f32x4 acc[4][2];
#pragma unroll
        for (int m = 0; m < 4; ++m)
#pragma unroll
            for (int j = 0; j < 2; ++j) acc[m][j] = (f32x4){0.f, 0.f, 0.f, 0.f};

        const ushort_t* kb = smem + cur * 12288;
#pragma unroll
        for (int h = 0; h < 2; ++h) {
            bf16x8 kf[4];
            // ---- plane Kh: terms (kh,ql),(kh,qm),(kh,qh)
#pragma unroll
            for (int m = 0; m < 4; ++m) {
                const int r = m * 16 + l15;
                const int slot = (h * 4 + l4) ^ (r & 7);
                kf[m] = *(const bf16x8*)(kb + 0 * 4096 + (size_t)(r * 8 + slot) * 8);
            }
#pragma unroll
            for (int m = 0; m < 4; ++m)
#pragma unroll
                for (int j = 0; j < 2; ++j) {
                    acc[m][j] = __builtin_amdgcn_mfma_f32_16x16x32_bf16(kf[m], qf[2][j][h], acc[m][j], 0, 0, 0);
                    acc[m][j] = __builtin_amdgcn_mfma_f32_16x16x32_bf16(kf[m], qf[1][j][h], acc[m][j], 0, 0, 0);
                    acc[m][j] = __builtin_amdgcn_mfma_f32_16x16x32_bf16(kf[m], qf[0][j][h], acc[m][j], 0, 0, 0);
                }
            // ---- plane Km: terms (km,qm),(km,qh)
#pragma unroll
            for (int m = 0; m < 4; ++m) {
                const int r = m * 16 + l15;
                const int slot = (h * 4 + l4) ^ (r & 7);
                kf[m] = *(const bf16x8*)(kb + 1 * 4096 + (size_t)(r * 8 + slot) * 8);
            }
#pragma unroll
            for (int m = 0; m < 4; ++m)
#pragma unroll
                for (int j = 0; j < 2; ++j) {
                    acc[m][j] = __builtin_amdgcn_mfma_f32_16x16x32_bf16(kf[m], qf[1][j][h], acc[m][j], 0, 0, 0);
                    acc[m][j] = __builtin_amdgcn_mfma_f32_16x16x32_bf16(kf[m], qf[0][j][h], acc[m][j], 0, 0, 0);
                }
            // ---- plane Kl: term (kl,qh)
#pragma unroll
            for (int m = 0; m < 4; ++m) {
                const int r = m * 16 + l15;
                const int slot = (h * 4 + l4) ^ (r & 7);
                kf[m] = *(const bf16x8*)(kb + 2 * 4096 + (size_t)(r * 8 + slot) * 8);
            }
#pragma unroll
            for (int m = 0; m < 4; ++m)
#pragma unroll
                for (int j = 0; j < 2; ++j)
                    acc[m][j] = __builtin_amdgcn_mfma_f32_16x16x32_bf16(kf[m], qf[0][j][h], acc[m][j], 0, 0, 0);
        }

        // ---- epilogue: lane holds k = kt*64 + m*16 + l4*4 + reg, q = col
#pragma unroll
        for (int j = 0; j < 2; ++j) {
            const int qrow  = wave * 32 + j * 16 + l15;
            const int qlrow = qt * 128 + qrow;
            const int qglob = qbase + qrow;
            const size_t srow = (srowQ + qlrow) * NTOK;
            const size_t mrow = (srowQ + qlrow) * NBLK8;
#pragma unroll
            for (int m = 0; m < 4; ++m) {
                const int kcol0 = kt * 64 + m * 16 + (l4 << 2);
                uint4 kv;
                kv.x = mono_key(acc[m][j][0] * 0.125f);
                kv.y = mono_key(acc[m][j][1] * 0.125f);
                kv.z = mono_key(acc[m][j][2] * 0.125f);
                kv.w = mono_key(acc[m][j][3] * 0.125f);
                *(uint4*)(S + srow + kcol0) = kv;
                // causal-masked 8-wide block max: 3 in-reg max + 1 shfl
                unsigned cm = (kcol0     <= qglob) ? kv.x : 0u;
                unsigned t;
                t = (kcol0 + 1 <= qglob) ? kv.y : 0u; cm = (t > cm) ? t : cm;
                t = (kcol0 + 2 <= qglob) ? kv.z : 0u; cm = (t > cm) ? t : cm;
                t = (kcol0 + 3 <= qglob) ? kv.w : 0u; cm = (t > cm) ? t : cm;
                const unsigned o = __shfl_xor(cm, 16, 64);
                cm = (o > cm) ? o : cm;
                if ((lane & 16) == 0) {
                    const int gblk = kt * 8 + m * 2 + (lane >> 5);
                    Smax[mrow + gblk] = cm;
                }
            }
        }

        if (more) {
            asm volatile("s_waitcnt vmcnt(16)" ::: "memory");
            __builtin_amdgcn_s_barrier();
            __builtin_amdgcn_sched_barrier(0);
        }
        cur ^= 1;
    }
#undef STAGE_K
}

// ---------------------------------------------------------------------------
// select_v7: hierarchical exact top-KSEL; V-gather 4-wide ILP-unrolled.
// [best-measured form]
// ---------------------------------------------------------------------------
__global__ __launch_bounds__(256) void select_v7(const unsigned* __restrict__ S,
                                                 const unsigned* __restrict__ Smax,
                                                 const float* __restrict__ V,
                                                 float* __restrict__ ctx,
                                                 float* __restrict__ attn,
                                                 int q0, int QC)
{
    __shared__ int   sBlkAll[4][KSEL];
    __shared__ int   sIdxAll[4][KSEL];
    __shared__ float sEAll[4][KSEL];

    const int lane = threadIdx.x & 63;
    const int wave = threadIdx.x >> 6;
    const int ql = blockIdx.x;
    const int b  = blockIdx.y >> 2;
    const int hg = blockIdx.y & 3;
    const int h  = hg * 4 + wave;
    const int q  = q0 + ql;
    const int L  = q + 1;
    const int nsel = (L < KSEL) ? L : KSEL;
    const int nb = (L + 7) >> 3;           // real 8-blocks in this row

    const size_t bhx = (size_t)(b * HEADS + h);
    const unsigned* Srow = S + (bhx * QC + ql) * NTOK;
    const unsigned* Mrow = Smax + (bhx * QC + ql) * NBLK8;
    const float* Vb   = V + bhx * NTOK * DHEAD;
    float* ctxRow  = ctx + (((size_t)(b * NTOK + q)) * HEADS + h) * DHEAD;
    float* attnRow = attn + ((size_t)(b * NTOK + q)) * NTOK;
    int*   sBlk = sBlkAll[wave];
    int*   sIdx = sIdxAll[wave];
    float* sE   = sEAll[wave];

    // ---- stage 1: block maxima (4 per lane; beyond-nb slots are stale -> 0)
    const uint4 bm4 = *(const uint4*)(Mrow + lane * 4);
    unsigned bmax[4] = {bm4.x, bm4.y, bm4.z, bm4.w};
#pragma unroll
    for (int s = 0; s < 4; ++s)
        if (lane * 4 + s >= nb) bmax[s] = 0u;

    unsigned gmax = bmax[0];
    gmax = (bmax[1] > gmax) ? bmax[1] : gmax;
    gmax = (bmax[2] > gmax) ? bmax[2] : gmax;
    gmax = (bmax[3] > gmax) ? bmax[3] : gmax;
#pragma unroll
    for (int d = 1; d < 64; d <<= 1) {
        const unsigned o = __shfl_xor(gmax, d, 64);
        gmax = (o > gmax) ? o : gmax;
    }
    const float vmax = unmono(gmax);

    unsigned selb = 0u;
    unsigned blkLo = 1u;
    int nselb;
    if (nb <= KSEL) {
        nselb = nb;
#pragma unroll
        for (int s = 0; s < 4; ++s)
            if (lane * 4 + s < nb) selb |= 1u << s;
    } else {
        nselb = KSEL;
        unsigned lo = 1u, hi = gmax >> 16;
        while (lo < hi) {
            const unsigned mid = lo + ((hi - lo + 1u) >> 1);
            const unsigned midk = mid << 16;
            int cnt = 0;
#pragma unroll
            for (int s = 0; s < 4; ++s)
                cnt += __popcll(__ballot(bmax[s] >= midk));
            if (cnt >= KSEL) lo = mid; else hi = mid - 1u;
        }
        blkLo = lo;
        const unsigned Tkb = lo << 16;
        const unsigned Gkb = Tkb | 0xFFFFu;
        int cge = 0, cgt = 0;
#pragma unroll
        for (int s = 0; s < 4; ++s) {
            cge += __popcll(__ballot(bmax[s] >= Tkb));
            cgt += __popcll(__ballot(bmax[s] > Gkb));
        }
        if (cge == KSEL) {
#pragma unroll
            for (int s = 0; s < 4; ++s)
                selb |= (bmax[s] >= Tkb) ? (1u << s) : 0u;
        } else {
            unsigned bmb = 0u;
#pragma unroll
            for (int s = 0; s < 4; ++s) {
                selb |= (bmax[s] > Gkb) ? (1u << s) : 0u;
                bmb  |= (bmax[s] >= Tkb && bmax[s] <= Gkb) ? (1u << s) : 0u;
            }
            int k_tie = KSEL - cgt;
            while (k_tie > 0) {
                u64 best = 0;
                unsigned bmm = bmb;
                while (bmm) {
                    const int s = __builtin_ctz(bmm);
                    bmm &= bmm - 1u;
                    const unsigned gblk = (unsigned)(lane * 4 + s);
                    const u64 k = ((u64)bmax[s] << 32) | (unsigned)~gblk;
                    if (k > best) best = k;
                }
                u64 bb = best;
#pragma unroll
                for (int d = 1; d < 64; d <<= 1) {
                    const u64 o = __shfl_xor(bb, d, 64);
                    bb = (o > bb) ? o : bb;
                }
                const unsigned gblk = ~(unsigned)bb;
                if (lane == (int)(gblk >> 2)) {
                    const unsigned bit = 1u << (gblk & 3u);
                    selb |= bit;
                    bmb &= ~bit;
                }
                --k_tie;
            }
        }
    }

    // ---- compact selected block ids into LDS (ascending by block index)
    {
        const int cb = __popc(selb);
        int pfxb = cb;
#pragma unroll
        for (int d = 1; d < 64; d <<= 1) {
            const int t = __shfl_up(pfxb, d, 64);
            if (lane >= d) pfxb += t;
        }
        pfxb -= cb;
        unsigned mskb = selb;
        int posb = pfxb;
        while (mskb) {
            const int s = __builtin_ctz(mskb);
            mskb &= mskb - 1u;
            sBlk[posb++] = lane * 4 + s;
        }
    }
    __asm volatile("s_waitcnt lgkmcnt(0)" ::: "memory");

    // ---- stage 2: gather candidates (<=256, 4/lane)
    const int NC = nselb * 8;
    unsigned km[4];
    int idx[4];
#pragma unroll
    for (int c = 0; c < 4; ++c) {
        const int t = c * 64 + lane;
        unsigned m = 0u;
        int j = 0;
        if (t < NC) {
            const int blk = sBlk[t >> 3];
            j = blk * 8 + (t & 7);
            if (j < L) m = Srow[j];
        }
        km[c] = m;
        idx[c] = j;
    }

    // exact element threshold (seeded: T_elem >= 32nd block max)
    unsigned lo = blkLo, hi = gmax >> 16;
    while (lo < hi) {
        const unsigned mid = lo + ((hi - lo + 1u) >> 1);
        const unsigned midk = mid << 16;
        int cnt = 0;
#pragma unroll
        for (int c = 0; c < 4; ++c)
            cnt += __popcll(__ballot(km[c] >= midk));
        if (cnt >= nsel) lo = mid; else hi = mid - 1u;
    }
    const unsigned Tk = lo << 16;
    const unsigned Gk = Tk | 0xFFFFu;

    int cnt_ge = 0, cnt_gt = 0;
#pragma unroll
    for (int c = 0; c < 4; ++c) {
        cnt_ge += __popcll(__ballot(km[c] >= Tk));
        cnt_gt += __popcll(__ballot(km[c] > Gk));
    }

    unsigned selmask = 0u;
    if (cnt_ge == nsel) {
#pragma unroll
        for (int c = 0; c < 4; ++c)
            selmask |= (km[c] >= Tk) ? (1u << c) : 0u;
    } else {
        unsigned bmask = 0u;
#pragma unroll
        for (int c = 0; c < 4; ++c) {
            selmask |= (km[c] > Gk) ? (1u << c) : 0u;
            bmask   |= (km[c] >= Tk && km[c] <= Gk) ? (1u << c) : 0u;
        }
        int k_tie = nsel - cnt_gt;
        while (k_tie > 0) {
            u64 best = 0;
            unsigned bmm = bmask;
            while (bmm) {
                const int c = __builtin_ctz(bmm);
                bmm &= bmm - 1u;
                const int t = c * 64 + lane;
                const u64 k = ((u64)km[c] << 32) |
                              ((u64)(0xFFFFu ^ (unsigned)idx[c]) << 16) | (u64)t;
                if (k > best) best = k;
            }
            u64 bb = best;
#pragma unroll
            for (int d = 1; d < 64; d <<= 1) {
                const u64 o = __shfl_xor(bb, d, 64);
                bb = (o > bb) ? o : bb;
            }
            const unsigned tt = (unsigned)bb & 0xFFFFu;
            if (lane == (int)(tt & 63u)) {
                const unsigned bit = 1u << (tt >> 6);
                selmask |= bit;
                bmask &= ~bit;
            }
            --k_tie;
        }
    }

    // ---- softmax over selected, attn scatter, ctx gather
    const int csel = __popc(selmask);
    int pfx = csel;
#pragma unroll
    for (int d = 1; d < 64; d <<= 1) {
        const int t = __shfl_up(pfx, d, 64);
        if (lane >= d) pfx += t;
    }
    pfx -= csel;

    float esum = 0.f;
    unsigned msk = selmask;
    int pos = pfx;
    while (msk) {
        const int c = __builtin_ctz(msk);
        msk &= msk - 1u;
        const float e = __expf(unmono(km[c]) - vmax);
        esum += e;
        sIdx[pos] = idx[c];
        sE[pos] = e;
        ++pos;
    }

    float Z = esum;
#pragma unroll
    for (int d = 1; d < 64; d <<= 1) Z += __shfl_xor(Z, d, 64);
    const float rcpZ = 1.0f / Z;

    msk = selmask;
    pos = pfx;
    while (msk) {
        const int c = __builtin_ctz(msk);
        msk &= msk - 1u;
        const float w = sE[pos] * rcpZ;
        ++pos;
        atomicAdd(&attnRow[idx[c]], w * (1.0f / (float)HEADS));
    }

    // ---- ctx gather: 4-wide unroll, 4 independent partial sums (ILP)
    {
        float a0 = 0.f, a1 = 0.f, a2 = 0.f, a3 = 0.f;
        int i = 0;
#pragma unroll 2
        for (; i + 4 <= nsel; i += 4) {
            const int i0 = sIdx[i],     i1 = sIdx[i + 1];
            const int i2 = sIdx[i + 2], i3 = sIdx[i + 3];
            const float w0 = sE[i]     * rcpZ, w1 = sE[i + 1] * rcpZ;
            const float w2 = sE[i + 2] * rcpZ, w3 = sE[i + 3] * rcpZ;
            a0 += w0 * Vb[(size_t)i0 * DHEAD + lane];
            a1 += w1 * Vb[(size_t)i1 * DHEAD + lane];
            a2 += w2 * Vb[(size_t)i2 * DHEAD + lane];
            a3 += w3 * Vb[(size_t)i3 * DHEAD + lane];
        }
        for (; i < nsel; ++i)
            a0 += sE[i] * rcpZ * Vb[(size_t)sIdx[i] * DHEAD + lane];
        ctxRow[lane] = (a0 + a1) + (a2 + a3);
    }
}

// ---------------------------------------------------------------------------
extern "C" void kernel_launch(void* const* d_in, const int* in_sizes, int n_in,
                              void* d_out, int out_size, void* d_ws, size_t ws_size,
                              hipStream_t stream) {
    const float* x  = (const float*)d_in[0];
    const float* Wq = (const float*)d_in[1];
    const float* bq = (const float*)d_in[2];
    const float* Wk = (const float*)d_in[3];
    const float* bk = (const float*)d_in[4];
    const float* Wv = (const float*)d_in[5];
    const float* bv = (const float*)d_in[6];
    const float* Wo = (const float*)d_in[7];
    const float* bo = (const float*)d_in[8];

    const size_t MB = 1ull << 20;
    char* wsb = (char*)d_ws;
    float*    Vws = (float*)(wsb + 0 * MB);     // 16 MB fp32 [b,h,n,d]
    float*    ctx = (float*)(wsb + 16 * MB);    // 16 MB fp32
    ushort_t* xhi = (ushort_t*)(wsb + 32 * MB); // 8 MB
    ushort_t* xlo = (ushort_t*)(wsb + 40 * MB); // 8 MB
    ushort_t* wqh = (ushort_t*)(wsb + 48 * MB); // 2 MB each
    ushort_t* wql = (ushort_t*)(wsb + 50 * MB);
    ushort_t* wkh = (ushort_t*)(wsb + 52 * MB);
    ushort_t* wkl = (ushort_t*)(wsb + 54 * MB);
    ushort_t* wvh = (ushort_t*)(wsb + 56 * MB);
    ushort_t* wvl = (ushort_t*)(wsb + 58 * MB);
    ushort_t* woh = (ushort_t*)(wsb + 60 * MB);
    ushort_t* wol = (ushort_t*)(wsb + 62 * MB);
    ushort_t* Qh  = (ushort_t*)(wsb + 64 * MB); // 8 MB each, [b,h,n,d]
    ushort_t* Qm  = (ushort_t*)(wsb + 72 * MB);
    ushort_t* Ql  = (ushort_t*)(wsb + 80 * MB);
    ushort_t* Kh  = (ushort_t*)(wsb + 88 * MB);
    ushort_t* Km  = (ushort_t*)(wsb + 96 * MB);
    ushort_t* Kl  = (ushort_t*)(wsb + 104 * MB);
    ushort_t* cxh = xhi;   // reuse (x splits dead after QKV projections)
    ushort_t* cxl = xlo;

    float* y    = (float*)d_out;
    float* attn = y + (size_t)BATCH * NTOK * DMODEL;

    const int NX = MROWS * DMODEL;
    const int NW = DMODEL * DMODEL;

    // ---- bf16 split conversions (gemm inputs)
    conv_split<<<NX / (256 * 4), 256, 0, stream>>>(x, xhi, xlo, NX);
    {
        dim3 cgrid(NW / (256 * 4), 4);
        conv_split4<<<cgrid, 256, 0, stream>>>(Wq, wqh, wql,
                                               Wk, wkh, wkl,
                                               Wv, wvh, wvl,
                                               Wo, woh, wol, NW);
    }

    // ---- fused Q/K/V projection (single kernel, shared A staging)
    dim3 ggrid(MROWS / 128, DMODEL / 64);
    gemm_qkv_fused<<<ggrid, 256, 0, stream>>>(xhi, xlo,
                                              wqh, wql, wkh, wkl, wvh, wvl,
                                              bq, bk, bv,
                                              Qh, Qm, Ql, Kh, Km, Kl, Vws);

    // ---- attention: q-chunk capped at 512 (S chunk 151 MB = LLC-resident)
    const size_t base_bytes = 112 * MB;
    const size_t avail = (ws_size > base_bytes) ? ws_size - base_bytes : 0;
    int QC = 128;
    for (int cand = 512; cand >= 128; cand >>= 1) {
        const size_t need = (size_t)BATCH * HEADS * cand * (size_t)(NTOK + NBLK8) * sizeof(unsigned);
        if (need <= avail) { QC = cand; break; }
    }
    unsigned* Smax = (unsigned*)(wsb + base_bytes);
    unsigned* Sws  = (unsigned*)(wsb + base_bytes +
                                 (size_t)BATCH * HEADS * QC * NBLK8 * sizeof(unsigned));

    const int nattn4 = BATCH * NTOK * NTOK / 4;
    zero_fill<<<(nattn4 + 255) / 256, 256, 0, stream>>>(attn, nattn4);
    for (int q0 = 0; q0 < NTOK; q0 += QC) {
        const int ktm = (q0 + QC) >> 6;
        dim3 sgrid((ktm + TPW - 1) / TPW, QC / 128, BATCH * HEADS);
        score_mfma<<<sgrid, 256, 0, stream>>>(Qh, Qm, Ql, Kh, Km, Kl, Sws, Smax, q0, QC);
        dim3 selgrid(QC, BATCH * 4);
        select_v7<<<selgrid, 256, 0, stream>>>(Sws, Smax, Vws, ctx, attn, q0, QC);
    }

    // ---- output projection
    conv_split<<<NX / (256 * 4), 256, 0, stream>>>(ctx, cxh, cxl, NX);
    gemm_split_mfma<<<ggrid, 256, 0, stream>>>(cxh, cxl, woh, wol, bo, y);
}

// Round 15
// 483.757 us; speedup vs baseline: 1.0490x; 1.0314x over previous
//
#include <hip/hip_runtime.h>
#include <hip/hip_bf16.h>
#include <math.h>

// Problem constants
#define BATCH   2
#define NTOK    2048
#define DMODEL  1024
#define HEADS   16
#define DHEAD   64
#define KSEL    32
#define MROWS   (BATCH * NTOK)   // 4096
#define NBLK8   (NTOK / 8)       // 256 8-wide key blocks per row
#define TPW     4                // k-tiles per score workgroup (best-measured)

typedef short     bf16x8 __attribute__((ext_vector_type(8)));
typedef float     f32x4  __attribute__((ext_vector_type(4)));
typedef unsigned short ushort_t;
typedef unsigned long long u64;

#define GLOAD_LDS16(g, l) \
    __builtin_amdgcn_global_load_lds((const __attribute__((address_space(1))) void*)(g), \
                                     (__attribute__((address_space(3))) void*)(l), 16, 0, 0)

// ---------------------------------------------------------------------------
// bf16 helpers
// ---------------------------------------------------------------------------
__device__ __forceinline__ ushort_t f2bf(float f) {
    unsigned u = __float_as_uint(f);
    unsigned r = (u + 0x7FFFu + ((u >> 16) & 1u)) >> 16;
    return (ushort_t)r;
}
__device__ __forceinline__ float bf2f(ushort_t h) {
    return __uint_as_float(((unsigned)h) << 16);
}

__device__ __forceinline__ void conv_body(const float* __restrict__ in,
                                          ushort_t* __restrict__ hi,
                                          ushort_t* __restrict__ lo, int n, int i)
{
    if (i + 3 < n) {
        const float4 v = *(const float4*)(in + i);
        ushort4 ph, pl;
        ph.x = f2bf(v.x); pl.x = f2bf(v.x - bf2f(ph.x));
        ph.y = f2bf(v.y); pl.y = f2bf(v.y - bf2f(ph.y));
        ph.z = f2bf(v.z); pl.z = f2bf(v.z - bf2f(ph.z));
        ph.w = f2bf(v.w); pl.w = f2bf(v.w - bf2f(ph.w));
        *(ushort4*)(hi + i) = ph;
        *(ushort4*)(lo + i) = pl;
    }
}

__global__ __launch_bounds__(256) void conv_split(const float* __restrict__ in,
                                                  ushort_t* __restrict__ hi,
                                                  ushort_t* __restrict__ lo, int n)
{
    const int i = (blockIdx.x * 256 + threadIdx.x) * 4;
    conv_body(in, hi, lo, n, i);
}

// 4 equal-size arrays in one launch (grid.y = which)
__global__ __launch_bounds__(256) void conv_split4(const float* __restrict__ i0, ushort_t* __restrict__ h0, ushort_t* __restrict__ l0,
                                                   const float* __restrict__ i1, ushort_t* __restrict__ h1, ushort_t* __restrict__ l1,
                                                   const float* __restrict__ i2, ushort_t* __restrict__ h2, ushort_t* __restrict__ l2,
                                                   const float* __restrict__ i3, ushort_t* __restrict__ h3, ushort_t* __restrict__ l3,
                                                   int n)
{
    const int w = blockIdx.y;
    const float* in = (w == 0) ? i0 : (w == 1) ? i1 : (w == 2) ? i2 : i3;
    ushort_t* hi = (w == 0) ? h0 : (w == 1) ? h1 : (w == 2) ? h2 : h3;
    ushort_t* lo = (w == 0) ? l0 : (w == 1) ? l1 : (w == 2) ? l2 : l3;
    const int i = (blockIdx.x * 256 + threadIdx.x) * 4;
    conv_body(in, hi, lo, n, i);
}

__global__ __launch_bounds__(256) void zero_fill(float* __restrict__ p, int n4)
{
    const int i = blockIdx.x * 256 + threadIdx.x;
    if (i < n4) ((float4*)p)[i] = (float4){0.f, 0.f, 0.f, 0.f};
}

// ---------------------------------------------------------------------------
// monotone key <-> float (bijective; order-preserving; 0 reserved for empty)
// ---------------------------------------------------------------------------
__device__ __forceinline__ unsigned mono_key(float f) {
    const unsigned u = __float_as_uint(f);
    return (u ^ (unsigned)(((int)u >> 31) | 0x80000000)) + 1u;
}
__device__ __forceinline__ float unmono(unsigned m) {
    const unsigned u = m - 1u;
    return __uint_as_float(u ^ (unsigned)(((int)(~u) >> 31) | 0x80000000));
}

// ---------------------------------------------------------------------------
// gemm_qkv_fused: Q/K/V projections in ONE kernel (shared A staging,
// 72 MFMAs per barrier). Natural blockIdx tile map. [best-measured form]
// ---------------------------------------------------------------------------
__global__ __launch_bounds__(256, 2) void gemm_qkv_fused(const ushort_t* __restrict__ xhi,
                                                         const ushort_t* __restrict__ xlo,
                                                         const ushort_t* __restrict__ wqh,
                                                         const ushort_t* __restrict__ wql,
                                                         const ushort_t* __restrict__ wkh,
                                                         const ushort_t* __restrict__ wkl,
                                                         const ushort_t* __restrict__ wvh,
                                                         const ushort_t* __restrict__ wvl,
                                                         const float* __restrict__ bq,
                                                         const float* __restrict__ bk,
                                                         const float* __restrict__ bv,
                                                         ushort_t* __restrict__ Qh,
                                                         ushort_t* __restrict__ Qm,
                                                         ushort_t* __restrict__ Ql,
                                                         ushort_t* __restrict__ Kh,
                                                         ushort_t* __restrict__ Km,
                                                         ushort_t* __restrict__ Kl,
                                                         float* __restrict__ Vws)
{
    __shared__ ushort_t smem[2 * 20480];   // 80 KB

    const int tid  = threadIdx.x;
    const int wave = tid >> 6;
    const int lane = tid & 63;
    const int fr   = lane & 15;
    const int k8   = lane >> 4;
    const int m0 = blockIdx.x * 128;
    const int n0 = blockIdx.y * 64;

    f32x4 acc[3][2][4];
#pragma unroll
    for (int w = 0; w < 3; ++w)
#pragma unroll
        for (int i = 0; i < 2; ++i)
#pragma unroll
            for (int j = 0; j < 4; ++j) acc[w][i][j] = (f32x4){0.f, 0.f, 0.f, 0.f};

#define STAGEF(bufsel, k0v) do {                                               \
        ushort_t* dst_ = smem + (size_t)(bufsel) * 20480;                      \
        _Pragma("unroll")                                                      \
        for (int i_ = 0; i_ < 2; ++i_) {                                       \
            const int c_ = i_ * 256 + tid;                                     \
            const int row_ = c_ >> 2;                                          \
            const int g_ = (c_ & 3) ^ ((row_ >> 1) & 3);                       \
            const size_t ga_ = (size_t)(m0 + row_) * DMODEL + (k0v) + g_ * 8;  \
            GLOAD_LDS16(xhi + ga_, dst_ + (size_t)c_ * 8);                     \
            GLOAD_LDS16(xlo + ga_, dst_ + 4096 + (size_t)c_ * 8);              \
        }                                                                      \
        {                                                                      \
            const int c_ = tid;                                                \
            const int row_ = c_ >> 2;                                          \
            const int g_ = (c_ & 3) ^ ((row_ >> 1) & 3);                       \
            const size_t gb_ = (size_t)(n0 + row_) * DMODEL + (k0v) + g_ * 8;  \
            GLOAD_LDS16(wqh + gb_, dst_ + 8192 + (size_t)c_ * 8);              \
            GLOAD_LDS16(wql + gb_, dst_ + 10240 + (size_t)c_ * 8);             \
            GLOAD_LDS16(wkh + gb_, dst_ + 12288 + (size_t)c_ * 8);             \
            GLOAD_LDS16(wkl + gb_, dst_ + 14336 + (size_t)c_ * 8);             \
            GLOAD_LDS16(wvh + gb_, dst_ + 16384 + (size_t)c_ * 8);             \
            GLOAD_LDS16(wvl + gb_, dst_ + 18432 + (size_t)c_ * 8);             \
        }                                                                      \
    } while (0)

    STAGEF(0, 0);
    int cur = 0;

    for (int k0 = 0; k0 < DMODEL; k0 += 32) {
        __syncthreads();                     // buf[cur] staged; prior reads done
        if (k0 + 32 < DMODEL) STAGEF(cur ^ 1, k0 + 32);

        const ushort_t* buf = smem + (size_t)cur * 20480;
        bf16x8 afh[2], afl[2];
#pragma unroll
        for (int mi = 0; mi < 2; ++mi) {
            const int r = wave * 32 + mi * 16 + fr;
            const int ro = r * 32 + (k8 ^ ((r >> 1) & 3)) * 8;
            afh[mi] = *(const bf16x8*)(buf + ro);
            afl[mi] = *(const bf16x8*)(buf + 4096 + ro);
        }

#pragma unroll
        for (int w = 0; w < 3; ++w) {
            const ushort_t* bb = buf + 8192 + w * 4096;
            bf16x8 bfh[4], bfl[4];
#pragma unroll
            for (int ni = 0; ni < 4; ++ni) {
                const int r = ni * 16 + fr;
                const int ro = r * 32 + (k8 ^ ((r >> 1) & 3)) * 8;
                bfh[ni] = *(const bf16x8*)(bb + ro);
                bfl[ni] = *(const bf16x8*)(bb + 2048 + ro);
            }
#pragma unroll
            for (int mi = 0; mi < 2; ++mi)
#pragma unroll
                for (int ni = 0; ni < 4; ++ni) {
                    acc[w][mi][ni] = __builtin_amdgcn_mfma_f32_16x16x32_bf16(afh[mi], bfl[ni], acc[w][mi][ni], 0, 0, 0);
                    acc[w][mi][ni] = __builtin_amdgcn_mfma_f32_16x16x32_bf16(afl[mi], bfh[ni], acc[w][mi][ni], 0, 0, 0);
                    acc[w][mi][ni] = __builtin_amdgcn_mfma_f32_16x16x32_bf16(afh[mi], bfh[ni], acc[w][mi][ni], 0, 0, 0);
                }
        }
        cur ^= 1;
    }
#undef STAGEF

    // ---- epilogue: Q (w=0) and K (w=1) -> 3-way split scatter; V (w=2) fp32
#pragma unroll
    for (int w = 0; w < 3; ++w) {
        const float* bias = (w == 0) ? bq : (w == 1) ? bk : bv;
        ushort_t* oh = (w == 0) ? Qh : Kh;
        ushort_t* om = (w == 0) ? Qm : Km;
        ushort_t* ol = (w == 0) ? Ql : Kl;
#pragma unroll
        for (int ni = 0; ni < 4; ++ni) {
            const int o = n0 + ni * 16 + (lane & 15);
            const float bvv = bias[o];
            const int hd = o >> 6;
            const int d  = o & 63;
#pragma unroll
            for (int mi = 0; mi < 2; ++mi) {
#pragma unroll
                for (int reg = 0; reg < 4; ++reg) {
                    const int m = m0 + wave * 32 + mi * 16 + ((lane >> 4) << 2) + reg;
                    const float v = acc[w][mi][ni][reg] + bvv;
                    const int bb = m >> 11;
                    const int n  = m & 2047;
                    const size_t off = (((size_t)(bb * HEADS + hd)) * NTOK + n) * DHEAD + d;
                    if (w == 2) {
                        Vws[off] = v;
                    } else {
                        const ushort_t h1 = f2bf(v);
                        const float r1 = v - bf2f(h1);
                        const ushort_t m1 = f2bf(r1);
                        const ushort_t l1 = f2bf(r1 - bf2f(m1));
                        oh[off] = h1; om[off] = m1; ol[off] = l1;
                    }
                }
            }
        }
    }
}

// ---------------------------------------------------------------------------
// Split-bf16 MFMA GEMM (2-buffer, Wo projection only). [best-measured form]
// ---------------------------------------------------------------------------
__global__ __launch_bounds__(256, 2) void gemm_split_mfma(const ushort_t* __restrict__ Ahi,
                                                          const ushort_t* __restrict__ Alo,
                                                          const ushort_t* __restrict__ Bhi,
                                                          const ushort_t* __restrict__ Blo,
                                                          const float* __restrict__ bias,
                                                          float* __restrict__ out)
{
    // per buffer: AH [0,4096) AL [4096,8192) BH [8192,10240) BL [10240,12288)
    __shared__ ushort_t smem[2 * 12288];   // 48 KB

    const int tid  = threadIdx.x;
    const int wave = tid >> 6;
    const int lane = tid & 63;
    const int fr   = lane & 15;
    const int k8   = lane >> 4;
    const int m0 = blockIdx.x * 128;
    const int n0 = blockIdx.y * 64;

    f32x4 acc[2][4];
#pragma unroll
    for (int i = 0; i < 2; ++i)
#pragma unroll
        for (int j = 0; j < 4; ++j) acc[i][j] = (f32x4){0.f, 0.f, 0.f, 0.f};

#define STAGE(bufsel, k0v) do {                                                \
        ushort_t* dst_ = smem + (size_t)(bufsel) * 12288;                      \
        _Pragma("unroll")                                                      \
        for (int i_ = 0; i_ < 2; ++i_) {                                       \
            const int c_ = i_ * 256 + tid;                                     \
            const int row_ = c_ >> 2;                                          \
            const int g_ = (c_ & 3) ^ ((row_ >> 1) & 3);                       \
            const size_t ga_ = (size_t)(m0 + row_) * DMODEL + (k0v) + g_ * 8;  \
            GLOAD_LDS16(Ahi + ga_, dst_ + (size_t)c_ * 8);                     \
            GLOAD_LDS16(Alo + ga_, dst_ + 4096 + (size_t)c_ * 8);              \
        }                                                                      \
        {                                                                      \
            const int c_ = tid;                                                \
            const int row_ = c_ >> 2;                                          \
            const int g_ = (c_ & 3) ^ ((row_ >> 1) & 3);                       \
            const size_t gb_ = (size_t)(n0 + row_) * DMODEL + (k0v) + g_ * 8;  \
            GLOAD_LDS16(Bhi + gb_, dst_ + 8192 + (size_t)c_ * 8);              \
            GLOAD_LDS16(Blo + gb_, dst_ + 10240 + (size_t)c_ * 8);             \
        }                                                                      \
    } while (0)

    STAGE(0, 0);
    int cur = 0;

    for (int k0 = 0; k0 < DMODEL; k0 += 32) {
        __syncthreads();                     // buf[cur] staged; prior reads done
        if (k0 + 32 < DMODEL) STAGE(cur ^ 1, k0 + 32);

        const ushort_t* buf = smem + (size_t)cur * 12288;
        bf16x8 afh[2], afl[2], bfh[4], bfl[4];
#pragma unroll
        for (int mi = 0; mi < 2; ++mi) {
            const int r = wave * 32 + mi * 16 + fr;
            const int ro = r * 32 + (k8 ^ ((r >> 1) & 3)) * 8;
            afh[mi] = *(const bf16x8*)(buf + ro);
            afl[mi] = *(const bf16x8*)(buf + 4096 + ro);
        }
#pragma unroll
        for (int ni = 0; ni < 4; ++ni) {
            const int r = ni * 16 + fr;
            const int ro = r * 32 + (k8 ^ ((r >> 1) & 3)) * 8;
            bfh[ni] = *(const bf16x8*)(buf + 8192 + ro);
            bfl[ni] = *(const bf16x8*)(buf + 10240 + ro);
        }

#pragma unroll
        for (int mi = 0; mi < 2; ++mi)
#pragma unroll
            for (int ni = 0; ni < 4; ++ni) {
                acc[mi][ni] = __builtin_amdgcn_mfma_f32_16x16x32_bf16(afh[mi], bfl[ni], acc[mi][ni], 0, 0, 0);
                acc[mi][ni] = __builtin_amdgcn_mfma_f32_16x16x32_bf16(afl[mi], bfh[ni], acc[mi][ni], 0, 0, 0);
                acc[mi][ni] = __builtin_amdgcn_mfma_f32_16x16x32_bf16(afh[mi], bfh[ni], acc[mi][ni], 0, 0, 0);
            }
        cur ^= 1;
    }
#undef STAGE

#pragma unroll
    for (int ni = 0; ni < 4; ++ni) {
        const int o = n0 + ni * 16 + (lane & 15);
        const float bv = bias[o];
#pragma unroll
        for (int mi = 0; mi < 2; ++mi) {
#pragma unroll
            for (int reg = 0; reg < 4; ++reg) {
                const int m = m0 + wave * 32 + mi * 16 + ((lane >> 4) << 2) + reg;
                out[(size_t)m * DMODEL + o] = acc[mi][ni][reg] + bv;
            }
        }
    }
}

// ---------------------------------------------------------------------------
// score_mfma v3: transposed MFMA (S^T tile = K·Q^T), fused kt loop.
// ---------------------------------------------------------------------------
__global__ __launch_bounds__(256, 3) void score_mfma(const ushort_t* __restrict__ Qh,
                                                     const ushort_t* __restrict__ Qm,
                                                     const ushort_t* __restrict__ Ql,
                                                     const ushort_t* __restrict__ Kh,
                                                     const ushort_t* __restrict__ Km,
                                                     const ushort_t* __restrict__ Kl,
                                                     unsigned* __restrict__ S,
                                                     unsigned* __restrict__ Smax,
                                                     int q0, int QC)
{
    const int ks = blockIdx.x;
    const int qt = blockIdx.y;
    const int bh = blockIdx.z;
    const int qbase = q0 + qt * 128;
    const int ktmax = ((qbase + 127) >> 6) + 1;   // tiles with any causal part
    const int kt0 = ks * TPW;
    if (kt0 >= ktmax) return;
    const int kt1 = (kt0 + TPW < ktmax) ? (kt0 + TPW) : ktmax;

    // 48 KB: 2 K buffers x 3 planes x 64 rows x 64 d
    __shared__ ushort_t smem[2 * 12288];

    const int tid  = threadIdx.x;
    const int wave = tid >> 6;
    const int lane = tid & 63;
    const int l15  = lane & 15;
    const int l4   = lane >> 4;

    const size_t qgbase = ((size_t)bh * NTOK + qbase) * DHEAD;

    // ---- Q fragments straight from global: qf[plane][j][h]
    bf16x8 qf[3][2][2];
#pragma unroll
    for (int p = 0; p < 3; ++p) {
        const ushort_t* Qp = (p == 0) ? Qh : (p == 1) ? Qm : Ql;
#pragma unroll
        for (int j = 0; j < 2; ++j) {
            const int r = wave * 32 + j * 16 + l15;
#pragma unroll
            for (int h = 0; h < 2; ++h)
                qf[p][j][h] = *(const bf16x8*)(Qp + qgbase + (size_t)r * DHEAD + (h * 4 + l4) * 8);
        }
    }

#define STAGE_K(bufsel, ktv) do {                                              \
        const size_t kg_ = ((size_t)bh * NTOK + (ktv) * 64) * DHEAD;           \
        _Pragma("unroll")                                                      \
        for (int i_ = 0; i_ < 2; ++i_) {                                       \
            const int c_ = i_ * 256 + tid;                                     \
            const int row_ = c_ >> 3;                                          \
            const int g_ = (c_ & 7) ^ (row_ & 7);                              \
            const size_t goff_ = kg_ + (size_t)row_ * DHEAD + g_ * 8;          \
            ushort_t* dst_ = smem + (bufsel) * 12288 + (size_t)c_ * 8;         \
            GLOAD_LDS16(Kh + goff_, dst_ + 0 * 4096);                          \
            GLOAD_LDS16(Km + goff_, dst_ + 1 * 4096);                          \
            GLOAD_LDS16(Kl + goff_, dst_ + 2 * 4096);                          \
        }                                                                      \
    } while (0)

    STAGE_K(0, kt0);
    __builtin_amdgcn_sched_barrier(0);
    asm volatile("s_waitcnt vmcnt(0)" ::: "memory");
    __builtin_amdgcn_s_barrier();
    __builtin_amdgcn_sched_barrier(0);

    int cur = 0;
    const size_t srowQ = (size_t)bh * QC;

    for (int kt = kt0; kt < kt1; ++kt) {
        const bool more = (kt + 1 < kt1);
        if (more) STAGE_K(cur ^ 1, kt + 1);
        __builtin_amdgcn_sched_barrier(0);   // pin staging loads before all else

        f32x4 acc[4][2];
#pragma unroll
        for (int m = 0; m < 4; ++m)
#pragma unroll
            for (int j = 0; j < 2; ++j) acc[m][j] = (f32x4){0.f, 0.f, 0.f, 0.f};

        const ushort_t* kb = smem + cur * 12288;
#pragma unroll
        for (int h = 0; h < 2; ++h) {
            bf16x8 kf[4];
            // ---- plane Kh: terms (kh,ql),(kh,qm),(kh,qh)
#pragma unroll
            for (int m = 0; m < 4; ++m) {
                const int r = m * 16 + l15;
                const int slot = (h * 4 + l4) ^ (r & 7);
                kf[m] = *(const bf16x8*)(kb + 0 * 4096 + (size_t)(r * 8 + slot) * 8);
            }
#pragma unroll
            for (int m = 0; m < 4; ++m)
#pragma unroll
                for (int j = 0; j < 2; ++j) {
                    acc[m][j] = __builtin_amdgcn_mfma_f32_16x16x32_bf16(kf[m], qf[2][j][h], acc[m][j], 0, 0, 0);
                    acc[m][j] = __builtin_amdgcn_mfma_f32_16x16x32_bf16(kf[m], qf[1][j][h], acc[m][j], 0, 0, 0);
                    acc[m][j] = __builtin_amdgcn_mfma_f32_16x16x32_bf16(kf[m], qf[0][j][h], acc[m][j], 0, 0, 0);
                }
            // ---- plane Km: terms (km,qm),(km,qh)
#pragma unroll
            for (int m = 0; m < 4; ++m) {
                const int r = m * 16 + l15;
                const int slot = (h * 4 + l4) ^ (r & 7);
                kf[m] = *(const bf16x8*)(kb + 1 * 4096 + (size_t)(r * 8 + slot) * 8);
            }
#pragma unroll
            for (int m = 0; m < 4; ++m)
#pragma unroll
                for (int j = 0; j < 2; ++j) {
                    acc[m][j] = __builtin_amdgcn_mfma_f32_16x16x32_bf16(kf[m], qf[1][j][h], acc[m][j], 0, 0, 0);
                    acc[m][j] = __builtin_amdgcn_mfma_f32_16x16x32_bf16(kf[m], qf[0][j][h], acc[m][j], 0, 0, 0);
                }
            // ---- plane Kl: term (kl,qh)
#pragma unroll
            for (int m = 0; m < 4; ++m) {
                const int r = m * 16 + l15;
                const int slot = (h * 4 + l4) ^ (r & 7);
                kf[m] = *(const bf16x8*)(kb + 2 * 4096 + (size_t)(r * 8 + slot) * 8);
            }
#pragma unroll
            for (int m = 0; m < 4; ++m)
#pragma unroll
                for (int j = 0; j < 2; ++j)
                    acc[m][j] = __builtin_amdgcn_mfma_f32_16x16x32_bf16(kf[m], qf[0][j][h], acc[m][j], 0, 0, 0);
        }

        // ---- epilogue: lane holds k = kt*64 + m*16 + l4*4 + reg, q = col
#pragma unroll
        for (int j = 0; j < 2; ++j) {
            const int qrow  = wave * 32 + j * 16 + l15;
            const int qlrow = qt * 128 + qrow;
            const int qglob = qbase + qrow;
            const size_t srow = (srowQ + qlrow) * NTOK;
            const size_t mrow = (srowQ + qlrow) * NBLK8;
#pragma unroll
            for (int m = 0; m < 4; ++m) {
                const int kcol0 = kt * 64 + m * 16 + (l4 << 2);
                uint4 kv;
                kv.x = mono_key(acc[m][j][0] * 0.125f);
                kv.y = mono_key(acc[m][j][1] * 0.125f);
                kv.z = mono_key(acc[m][j][2] * 0.125f);
                kv.w = mono_key(acc[m][j][3] * 0.125f);
                *(uint4*)(S + srow + kcol0) = kv;
                // causal-masked 8-wide block max: 3 in-reg max + 1 shfl
                unsigned cm = (kcol0     <= qglob) ? kv.x : 0u;
                unsigned t;
                t = (kcol0 + 1 <= qglob) ? kv.y : 0u; cm = (t > cm) ? t : cm;
                t = (kcol0 + 2 <= qglob) ? kv.z : 0u; cm = (t > cm) ? t : cm;
                t = (kcol0 + 3 <= qglob) ? kv.w : 0u; cm = (t > cm) ? t : cm;
                const unsigned o = __shfl_xor(cm, 16, 64);
                cm = (o > cm) ? o : cm;
                if ((lane & 16) == 0) {
                    const int gblk = kt * 8 + m * 2 + (lane >> 5);
                    Smax[mrow + gblk] = cm;
                }
            }
        }

        if (more) {
            asm volatile("s_waitcnt vmcnt(16)" ::: "memory");
            __builtin_amdgcn_s_barrier();
            __builtin_amdgcn_sched_barrier(0);
        }
        cur ^= 1;
    }
#undef STAGE_K
}

// ---------------------------------------------------------------------------
// select_v7: hierarchical exact top-KSEL; V-gather 4-wide ILP-unrolled.
// [best-measured form]
// ---------------------------------------------------------------------------
__global__ __launch_bounds__(256) void select_v7(const unsigned* __restrict__ S,
                                                 const unsigned* __restrict__ Smax,
                                                 const float* __restrict__ V,
                                                 float* __restrict__ ctx,
                                                 float* __restrict__ attn,
                                                 int q0, int QC)
{
    __shared__ int   sBlkAll[4][KSEL];
    __shared__ int   sIdxAll[4][KSEL];
    __shared__ float sEAll[4][KSEL];

    const int lane = threadIdx.x & 63;
    const int wave = threadIdx.x >> 6;
    const int ql = blockIdx.x;
    const int b  = blockIdx.y >> 2;
    const int hg = blockIdx.y & 3;
    const int h  = hg * 4 + wave;
    const int q  = q0 + ql;
    const int L  = q + 1;
    const int nsel = (L < KSEL) ? L : KSEL;
    const int nb = (L + 7) >> 3;           // real 8-blocks in this row

    const size_t bhx = (size_t)(b * HEADS + h);
    const unsigned* Srow = S + (bhx * QC + ql) * NTOK;
    const unsigned* Mrow = Smax + (bhx * QC + ql) * NBLK8;
    const float* Vb   = V + bhx * NTOK * DHEAD;
    float* ctxRow  = ctx + (((size_t)(b * NTOK + q)) * HEADS + h) * DHEAD;
    float* attnRow = attn + ((size_t)(b * NTOK + q)) * NTOK;
    int*   sBlk = sBlkAll[wave];
    int*   sIdx = sIdxAll[wave];
    float* sE   = sEAll[wave];

    // ---- stage 1: block maxima (4 per lane; beyond-nb slots are stale -> 0)
    const uint4 bm4 = *(const uint4*)(Mrow + lane * 4);
    unsigned bmax[4] = {bm4.x, bm4.y, bm4.z, bm4.w};
#pragma unroll
    for (int s = 0; s < 4; ++s)
        if (lane * 4 + s >= nb) bmax[s] = 0u;

    unsigned gmax = bmax[0];
    gmax = (bmax[1] > gmax) ? bmax[1] : gmax;
    gmax = (bmax[2] > gmax) ? bmax[2] : gmax;
    gmax = (bmax[3] > gmax) ? bmax[3] : gmax;
#pragma unroll
    for (int d = 1; d < 64; d <<= 1) {
        const unsigned o = __shfl_xor(gmax, d, 64);
        gmax = (o > gmax) ? o : gmax;
    }
    const float vmax = unmono(gmax);

    unsigned selb = 0u;
    unsigned blkLo = 1u;
    int nselb;
    if (nb <= KSEL) {
        nselb = nb;
#pragma unroll
        for (int s = 0; s < 4; ++s)
            if (lane * 4 + s < nb) selb |= 1u << s;
    } else {
        nselb = KSEL;
        unsigned lo = 1u, hi = gmax >> 16;
        while (lo < hi) {
            const unsigned mid = lo + ((hi - lo + 1u) >> 1);
            const unsigned midk = mid << 16;
            int cnt = 0;
#pragma unroll
            for (int s = 0; s < 4; ++s)
                cnt += __popcll(__ballot(bmax[s] >= midk));
            if (cnt >= KSEL) lo = mid; else hi = mid - 1u;
        }
        blkLo = lo;
        const unsigned Tkb = lo << 16;
        const unsigned Gkb = Tkb | 0xFFFFu;
        int cge = 0, cgt = 0;
#pragma unroll
        for (int s = 0; s < 4; ++s) {
            cge += __popcll(__ballot(bmax[s] >= Tkb));
            cgt += __popcll(__ballot(bmax[s] > Gkb));
        }
        if (cge == KSEL) {
#pragma unroll
            for (int s = 0; s < 4; ++s)
                selb |= (bmax[s] >= Tkb) ? (1u << s) : 0u;
        } else {
            unsigned bmb = 0u;
#pragma unroll
            for (int s = 0; s < 4; ++s) {
                selb |= (bmax[s] > Gkb) ? (1u << s) : 0u;
                bmb  |= (bmax[s] >= Tkb && bmax[s] <= Gkb) ? (1u << s) : 0u;
            }
            int k_tie = KSEL - cgt;
            while (k_tie > 0) {
                u64 best = 0;
                unsigned bmm = bmb;
                while (bmm) {
                    const int s = __builtin_ctz(bmm);
                    bmm &= bmm - 1u;
                    const unsigned gblk = (unsigned)(lane * 4 + s);
                    const u64 k = ((u64)bmax[s] << 32) | (unsigned)~gblk;
                    if (k > best) best = k;
                }
                u64 bb = best;
#pragma unroll
                for (int d = 1; d < 64; d <<= 1) {
                    const u64 o = __shfl_xor(bb, d, 64);
                    bb = (o > bb) ? o : bb;
                }
                const unsigned gblk = ~(unsigned)bb;
                if (lane == (int)(gblk >> 2)) {
                    const unsigned bit = 1u << (gblk & 3u);
                    selb |= bit;
                    bmb &= ~bit;
                }
                --k_tie;
            }
        }
    }

    // ---- compact selected block ids into LDS (ascending by block index)
    {
        const int cb = __popc(selb);
        int pfxb = cb;
#pragma unroll
        for (int d = 1; d < 64; d <<= 1) {
            const int t = __shfl_up(pfxb, d, 64);
            if (lane >= d) pfxb += t;
        }
        pfxb -= cb;
        unsigned mskb = selb;
        int posb = pfxb;
        while (mskb) {
            const int s = __builtin_ctz(mskb);
            mskb &= mskb - 1u;
            sBlk[posb++] = lane * 4 + s;
        }
    }
    __asm volatile("s_waitcnt lgkmcnt(0)" ::: "memory");

    // ---- stage 2: gather candidates (<=256, 4/lane)
    const int NC = nselb * 8;
    unsigned km[4];
    int idx[4];
#pragma unroll
    for (int c = 0; c < 4; ++c) {
        const int t = c * 64 + lane;
        unsigned m = 0u;
        int j = 0;
        if (t < NC) {
            const int blk = sBlk[t >> 3];
            j = blk * 8 + (t & 7);
            if (j < L) m = Srow[j];
        }
        km[c] = m;
        idx[c] = j;
    }

    // exact element threshold (seeded: T_elem >= 32nd block max)
    unsigned lo = blkLo, hi = gmax >> 16;
    while (lo < hi) {
        const unsigned mid = lo + ((hi - lo + 1u) >> 1);
        const unsigned midk = mid << 16;
        int cnt = 0;
#pragma unroll
        for (int c = 0; c < 4; ++c)
            cnt += __popcll(__ballot(km[c] >= midk));
        if (cnt >= nsel) lo = mid; else hi = mid - 1u;
    }
    const unsigned Tk = lo << 16;
    const unsigned Gk = Tk | 0xFFFFu;

    int cnt_ge = 0, cnt_gt = 0;
#pragma unroll
    for (int c = 0; c < 4; ++c) {
        cnt_ge += __popcll(__ballot(km[c] >= Tk));
        cnt_gt += __popcll(__ballot(km[c] > Gk));
    }

    unsigned selmask = 0u;
    if (cnt_ge == nsel) {
#pragma unroll
        for (int c = 0; c < 4; ++c)
            selmask |= (km[c] >= Tk) ? (1u << c) : 0u;
    } else {
        unsigned bmask = 0u;
#pragma unroll
        for (int c = 0; c < 4; ++c) {
            selmask |= (km[c] > Gk) ? (1u << c) : 0u;
            bmask   |= (km[c] >= Tk && km[c] <= Gk) ? (1u << c) : 0u;
        }
        int k_tie = nsel - cnt_gt;
        while (k_tie > 0) {
            u64 best = 0;
            unsigned bmm = bmask;
            while (bmm) {
                const int c = __builtin_ctz(bmm);
                bmm &= bmm - 1u;
                const int t = c * 64 + lane;
                const u64 k = ((u64)km[c] << 32) |
                              ((u64)(0xFFFFu ^ (unsigned)idx[c]) << 16) | (u64)t;
                if (k > best) best = k;
            }
            u64 bb = best;
#pragma unroll
            for (int d = 1; d < 64; d <<= 1) {
                const u64 o = __shfl_xor(bb, d, 64);
                bb = (o > bb) ? o : bb;
            }
            const unsigned tt = (unsigned)bb & 0xFFFFu;
            if (lane == (int)(tt & 63u)) {
                const unsigned bit = 1u << (tt >> 6);
                selmask |= bit;
                bmask &= ~bit;
            }
            --k_tie;
        }
    }

    // ---- softmax over selected, attn scatter, ctx gather
    const int csel = __popc(selmask);
    int pfx = csel;
#pragma unroll
    for (int d = 1; d < 64; d <<= 1) {
        const int t = __shfl_up(pfx, d, 64);
        if (lane >= d) pfx += t;
    }
    pfx -= csel;

    float esum = 0.f;
    unsigned msk = selmask;
    int pos = pfx;
    while (msk) {
        const int c = __builtin_ctz(msk);
        msk &= msk - 1u;
        const float e = __expf(unmono(km[c]) - vmax);
        esum += e;
        sIdx[pos] = idx[c];
        sE[pos] = e;
        ++pos;
    }

    float Z = esum;
#pragma unroll
    for (int d = 1; d < 64; d <<= 1) Z += __shfl_xor(Z, d, 64);
    const float rcpZ = 1.0f / Z;

    msk = selmask;
    pos = pfx;
    while (msk) {
        const int c = __builtin_ctz(msk);
        msk &= msk - 1u;
        const float w = sE[pos] * rcpZ;
        ++pos;
        atomicAdd(&attnRow[idx[c]], w * (1.0f / (float)HEADS));
    }

    // ---- ctx gather: 4-wide unroll, 4 independent partial sums (ILP)
    {
        float a0 = 0.f, a1 = 0.f, a2 = 0.f, a3 = 0.f;
        int i = 0;
#pragma unroll 2
        for (; i + 4 <= nsel; i += 4) {
            const int i0 = sIdx[i],     i1 = sIdx[i + 1];
            const int i2 = sIdx[i + 2], i3 = sIdx[i + 3];
            const float w0 = sE[i]     * rcpZ, w1 = sE[i + 1] * rcpZ;
            const float w2 = sE[i + 2] * rcpZ, w3 = sE[i + 3] * rcpZ;
            a0 += w0 * Vb[(size_t)i0 * DHEAD + lane];
            a1 += w1 * Vb[(size_t)i1 * DHEAD + lane];
            a2 += w2 * Vb[(size_t)i2 * DHEAD + lane];
            a3 += w3 * Vb[(size_t)i3 * DHEAD + lane];
        }
        for (; i < nsel; ++i)
            a0 += sE[i] * rcpZ * Vb[(size_t)sIdx[i] * DHEAD + lane];
        ctxRow[lane] = (a0 + a1) + (a2 + a3);
    }
}

// ---------------------------------------------------------------------------
extern "C" void kernel_launch(void* const* d_in, const int* in_sizes, int n_in,
                              void* d_out, int out_size, void* d_ws, size_t ws_size,
                              hipStream_t stream) {
    const float* x  = (const float*)d_in[0];
    const float* Wq = (const float*)d_in[1];
    const float* bq = (const float*)d_in[2];
    const float* Wk = (const float*)d_in[3];
    const float* bk = (const float*)d_in[4];
    const float* Wv = (const float*)d_in[5];
    const float* bv = (const float*)d_in[6];
    const float* Wo = (const float*)d_in[7];
    const float* bo = (const float*)d_in[8];

    const size_t MB = 1ull << 20;
    char* wsb = (char*)d_ws;
    float*    Vws = (float*)(wsb + 0 * MB);     // 16 MB fp32 [b,h,n,d]
    float*    ctx = (float*)(wsb + 16 * MB);    // 16 MB fp32
    ushort_t* xhi = (ushort_t*)(wsb + 32 * MB); // 8 MB
    ushort_t* xlo = (ushort_t*)(wsb + 40 * MB); // 8 MB
    ushort_t* wqh = (ushort_t*)(wsb + 48 * MB); // 2 MB each
    ushort_t* wql = (ushort_t*)(wsb + 50 * MB);
    ushort_t* wkh = (ushort_t*)(wsb + 52 * MB);
    ushort_t* wkl = (ushort_t*)(wsb + 54 * MB);
    ushort_t* wvh = (ushort_t*)(wsb + 56 * MB);
    ushort_t* wvl = (ushort_t*)(wsb + 58 * MB);
    ushort_t* woh = (ushort_t*)(wsb + 60 * MB);
    ushort_t* wol = (ushort_t*)(wsb + 62 * MB);
    ushort_t* Qh  = (ushort_t*)(wsb + 64 * MB); // 8 MB each, [b,h,n,d]
    ushort_t* Qm  = (ushort_t*)(wsb + 72 * MB);
    ushort_t* Ql  = (ushort_t*)(wsb + 80 * MB);
    ushort_t* Kh  = (ushort_t*)(wsb + 88 * MB);
    ushort_t* Km  = (ushort_t*)(wsb + 96 * MB);
    ushort_t* Kl  = (ushort_t*)(wsb + 104 * MB);
    ushort_t* cxh = xhi;   // reuse (x splits dead after QKV projections)
    ushort_t* cxl = xlo;

    float* y    = (float*)d_out;
    float* attn = y + (size_t)BATCH * NTOK * DMODEL;

    const int NX = MROWS * DMODEL;
    const int NW = DMODEL * DMODEL;

    // ---- bf16 split conversions (gemm inputs)
    conv_split<<<NX / (256 * 4), 256, 0, stream>>>(x, xhi, xlo, NX);
    {
        dim3 cgrid(NW / (256 * 4), 4);
        conv_split4<<<cgrid, 256, 0, stream>>>(Wq, wqh, wql,
                                               Wk, wkh, wkl,
                                               Wv, wvh, wvl,
                                               Wo, woh, wol, NW);
    }

    // ---- fused Q/K/V projection (single kernel, shared A staging)
    dim3 ggrid(MROWS / 128, DMODEL / 64);
    gemm_qkv_fused<<<ggrid, 256, 0, stream>>>(xhi, xlo,
                                              wqh, wql, wkh, wkl, wvh, wvl,
                                              bq, bk, bv,
                                              Qh, Qm, Ql, Kh, Km, Kl, Vws);

    // ---- attention: q-chunk capped at 512 (S chunk 151 MB = LLC-resident)
    const size_t base_bytes = 112 * MB;
    const size_t avail = (ws_size > base_bytes) ? ws_size - base_bytes : 0;
    int QC = 128;
    for (int cand = 512; cand >= 128; cand >>= 1) {
        const size_t need = (size_t)BATCH * HEADS * cand * (size_t)(NTOK + NBLK8) * sizeof(unsigned);
        if (need <= avail) { QC = cand; break; }
    }
    unsigned* Smax = (unsigned*)(wsb + base_bytes);
    unsigned* Sws  = (unsigned*)(wsb + base_bytes +
                                 (size_t)BATCH * HEADS * QC * NBLK8 * sizeof(unsigned));

    const int nattn4 = BATCH * NTOK * NTOK / 4;
    zero_fill<<<(nattn4 + 255) / 256, 256, 0, stream>>>(attn, nattn4);
    for (int q0 = 0; q0 < NTOK; q0 += QC) {
        const int ktm = (q0 + QC) >> 6;
        dim3 sgrid((ktm + TPW - 1) / TPW, QC / 128, BATCH * HEADS);
        score_mfma<<<sgrid, 256, 0, stream>>>(Qh, Qm, Ql, Kh, Km, Kl, Sws, Smax, q0, QC);
        dim3 selgrid(QC, BATCH * 4);
        select_v7<<<selgrid, 256, 0, stream>>>(Sws, Smax, Vws, ctx, attn, q0, QC);
    }

    // ---- output projection
    conv_split<<<NX / (256 * 4), 256, 0, stream>>>(ctx, cxh, cxl, NX);
    gemm_split_mfma<<<ggrid, 256, 0, stream>>>(cxh, cxl, woh, wol, bo, y);
}